// Round 1
// baseline (1359.374 us; speedup 1.0000x reference)
//
#include <hip/hip_runtime.h>

#define Bn 4
#define Cc 64
#define CQn 8
#define Hh 256
#define Ww 256
#define PLANE 65536

// ---------- Kernel 1: axial depthwise conv + relu + pointwise ----------
__global__ __launch_bounds__(256) void conv_pw_kernel(
    const float* __restrict__ x,
    const float* __restrict__ hw, const float* __restrict__ hb,
    const float* __restrict__ vw, const float* __restrict__ vb,
    const float* __restrict__ pww, const float* __restrict__ pwb,
    float* __restrict__ y_raw)
{
    int blk = blockIdx.x;
    int b = blk >> 8;
    int h = blk & 255;
    int w = threadIdx.x;
    __shared__ float row[Cc][Ww + 4];
    const float* xb = x + (size_t)b * Cc * PLANE;
    float a[Cc];

    #pragma unroll
    for (int c = 0; c < Cc; ++c) {
        float xv = xb[c * PLANE + h * Ww + w];
        row[c][w + 2] = xv;
        a[c] = xv;
    }
    if (w < 4) {
        int idx = (w < 2) ? w : (Ww + w);  // 0,1,258,259
        #pragma unroll
        for (int c = 0; c < Cc; ++c) row[c][idx] = 0.f;
    }
    __syncthreads();

    #pragma unroll
    for (int c = 0; c < Cc; ++c) {
        float hsum = 0.f;
        #pragma unroll
        for (int t = 0; t < 5; ++t) hsum += hw[c * 5 + t] * row[c][w + t];
        float vsum = 0.f;
        #pragma unroll
        for (int t = 0; t < 5; ++t) {
            int hh2 = h - 2 + t;
            float xv;
            if (t == 2) xv = a[c];
            else xv = (hh2 >= 0 && hh2 < Hh) ? xb[c * PLANE + hh2 * Ww + w] : 0.f;
            vsum += vw[c * 5 + t] * xv;
        }
        float v = hsum + hb[c] + vsum + vb[c] + a[c];
        a[c] = fmaxf(v, 0.f);
    }

    size_t ybase = (size_t)b * Cc * PLANE + h * Ww + w;
    for (int o = 0; o < Cc; ++o) {
        float acc = pwb[o];
        #pragma unroll
        for (int c = 0; c < Cc; ++c) acc += pww[o * Cc + c] * a[c];
        y_raw[ybase + (size_t)o * PLANE] = acc;
    }
}

// ---------- Kernel 2: per-(b,c) plane sum / sumsq ----------
__global__ __launch_bounds__(256) void stats_kernel(
    const float* __restrict__ y, float* __restrict__ sums, float* __restrict__ sumsq)
{
    int bc = blockIdx.x;
    const float* p = y + (size_t)bc * PLANE;
    float s = 0.f, s2 = 0.f;
    for (int i = threadIdx.x; i < PLANE; i += 256) {
        float v = p[i];
        s += v; s2 += v * v;
    }
    #pragma unroll
    for (int off = 32; off > 0; off >>= 1) {
        s  += __shfl_down(s, off);
        s2 += __shfl_down(s2, off);
    }
    __shared__ float red[8];
    int lane = threadIdx.x & 63, wv = threadIdx.x >> 6;
    if (lane == 0) { red[wv] = s; red[4 + wv] = s2; }
    __syncthreads();
    if (threadIdx.x == 0) {
        float a = 0.f, b2 = 0.f;
        for (int i = 0; i < 4; ++i) { a += red[i]; b2 += red[4 + i]; }
        sums[bc] = a; sumsq[bc] = b2;
    }
}

// ---------- Kernel 3: fold hybrid norm into per-(b,c) affine ----------
__global__ void finalize_kernel(
    const float* __restrict__ sums, const float* __restrict__ sumsq,
    const float* __restrict__ bn_w, const float* __restrict__ bn_b,
    float* __restrict__ alpha, float* __restrict__ beta)
{
    int c = threadIdx.x;
    if (c >= Cc) return;
    float im[4], e2[4];
    float bm = 0.f, be2 = 0.f;
    for (int b = 0; b < 4; ++b) {
        im[b] = sums[b * Cc + c] * (1.f / 65536.f);
        e2[b] = sumsq[b * Cc + c] * (1.f / 65536.f);
        bm += im[b]; be2 += e2[b];
    }
    bm *= 0.25f; be2 *= 0.25f;
    float bv = be2 - bm * bm;
    float rsb = rsqrtf(bv + 1e-5f);
    float wgt = bn_w[c], bb = bn_b[c];
    for (int b = 0; b < 4; ++b) {
        float iv = e2[b] - im[b] * im[b];
        float rsi = rsqrtf(iv + 1e-5f);
        float al = 0.7f * rsi + 0.3f * rsb * wgt;
        float bt = -0.7f * im[b] * rsi - 0.3f * bm * rsb * wgt + 0.3f * bb;
        alpha[b * Cc + c] = al;
        beta[b * Cc + c] = bt;
    }
}

// ---------- Kernel 4: normalize + q/k/v projections ----------
__global__ __launch_bounds__(256) void qkv_kernel(
    const float* __restrict__ y_raw,
    const float* __restrict__ alpha, const float* __restrict__ beta,
    const float* __restrict__ qw, const float* __restrict__ qbias,
    const float* __restrict__ kw, const float* __restrict__ kbias,
    const float* __restrict__ vw, const float* __restrict__ vbias,
    float* __restrict__ y_norm, float* __restrict__ q, float* __restrict__ k,
    float* __restrict__ val)
{
    int blk = blockIdx.x;
    int b = blk >> 8;
    int h = blk & 255;
    int w = threadIdx.x;
    size_t base = (size_t)b * Cc * PLANE + h * Ww + w;
    float y[Cc];
    #pragma unroll
    for (int c = 0; c < Cc; ++c) {
        float v = y_raw[base + (size_t)c * PLANE];
        v = alpha[b * Cc + c] * v + beta[b * Cc + c];
        y[c] = v;
        y_norm[base + (size_t)c * PLANE] = v;
    }
    size_t qbase = (size_t)b * CQn * PLANE + h * Ww + w;
    for (int o = 0; o < CQn; ++o) {
        float aq = qbias[o], ak = kbias[o];
        #pragma unroll
        for (int c = 0; c < Cc; ++c) {
            aq += qw[o * Cc + c] * y[c];
            ak += kw[o * Cc + c] * y[c];
        }
        q[qbase + (size_t)o * PLANE] = aq;
        k[qbase + (size_t)o * PLANE] = ak;
    }
    for (int o = 0; o < Cc; ++o) {
        float av = vbias[o];
        #pragma unroll
        for (int c = 0; c < Cc; ++c) av += vw[o * Cc + c] * y[c];
        val[base + (size_t)o * PLANE] = av;
    }
}

// ---------- Kernel 5: batched 256x256 plane transpose ----------
__global__ __launch_bounds__(256) void transpose_kernel(
    const float* __restrict__ src, float* __restrict__ dst)
{
    int blk = blockIdx.x;
    int plane = blk >> 6;
    int tile = blk & 63;
    int th = (tile >> 3) * 32;
    int tw = (tile & 7) * 32;
    __shared__ float t[32][33];
    const float* s = src + (size_t)plane * PLANE;
    float* d = dst + (size_t)plane * PLANE;
    int lw = threadIdx.x & 31;
    int lh = threadIdx.x >> 5;  // 0..7
    #pragma unroll
    for (int i = 0; i < 4; ++i)
        t[lh + 8 * i][lw] = s[(th + lh + 8 * i) * Ww + tw + lw];
    __syncthreads();
    #pragma unroll
    for (int i = 0; i < 4; ++i)
        d[(tw + lh + 8 * i) * Hh + th + lw] = t[lw][lh + 8 * i];
}

// ---------- Kernel 6: generic row attention (softmax over last axis keys) ----------
// S[j][i] = sum_c q[c][j]*k[c][i]; A = exp(S - m[j]) / l[j];
// out[c][i] = sum_j val[c][j] * A[j][i]
__global__ __launch_bounds__(256) void attn_kernel(
    const float* __restrict__ q, const float* __restrict__ k,
    const float* __restrict__ val, float* __restrict__ out)
{
    int blk = blockIdx.x;
    int b = blk >> 8;
    int r = blk & 255;
    int tid = threadIdx.x;
    __shared__ float qs[256][8];
    __shared__ float ks[256][8];
    __shared__ float vs[256][68];   // pad 68: 16B-aligned rows, staging conflicts <=8-way
    __shared__ float mlb[256][2];

    size_t qbase = (size_t)b * CQn * PLANE + (size_t)r * Ww;
    float qreg[8], kreg[8];
    #pragma unroll
    for (int c = 0; c < 8; ++c) {
        float qv = q[qbase + (size_t)c * PLANE + tid];
        float kv = k[qbase + (size_t)c * PLANE + tid];
        qs[tid][c] = qv; ks[tid][c] = kv;
        qreg[c] = qv; kreg[c] = kv;
    }
    size_t vbase = (size_t)b * Cc * PLANE + (size_t)r * Ww;
    #pragma unroll 8
    for (int c = 0; c < Cc; ++c) vs[tid][c] = val[vbase + (size_t)c * PLANE + tid];
    __syncthreads();

    // pass 1: thread = query row j, online softmax stats over keys i
    float m = -1e30f, l = 0.f;
    for (int i = 0; i < 256; ++i) {
        float s = 0.f;
        #pragma unroll
        for (int c = 0; c < 8; ++c) s += qreg[c] * ks[i][c];
        float nm = fmaxf(m, s);
        l = l * __expf(m - nm) + __expf(s - nm);
        m = nm;
    }
    mlb[tid][0] = m;
    mlb[tid][1] = 1.f / l;
    __syncthreads();

    // pass 2: thread = output position i, accumulate over queries j
    float acc[Cc];
    #pragma unroll
    for (int c = 0; c < Cc; ++c) acc[c] = 0.f;
    for (int j = 0; j < 256; ++j) {
        float s = 0.f;
        #pragma unroll
        for (int c = 0; c < 8; ++c) s += qs[j][c] * kreg[c];
        float aw = __expf(s - mlb[j][0]) * mlb[j][1];
        #pragma unroll
        for (int c = 0; c < Cc; ++c) acc[c] += aw * vs[j][c];
    }
    #pragma unroll
    for (int c = 0; c < Cc; ++c) out[vbase + (size_t)c * PLANE + tid] = acc[c];
}

// ---------- Kernel 7: combine + residual + 2x2 maxpool ----------
__global__ __launch_bounds__(256) void final_kernel(
    const float* __restrict__ houtT, const float* __restrict__ y_norm,
    const float* __restrict__ gamma,
    float* __restrict__ out, float* __restrict__ down)
{
    int blk = blockIdx.x;
    int tile = blk & 63;
    int bc = blk >> 6;   // b*64 + c
    int th = (tile >> 3) * 32;
    int tw = (tile & 7) * 32;
    __shared__ float t[32][33];
    const float* hT = houtT + (size_t)bc * PLANE;
    {
        int ww = threadIdx.x >> 3;        // 0..31
        int hh = (threadIdx.x & 7) * 4;   // 0..28
        const float4 v4 = *(const float4*)(hT + (size_t)(tw + ww) * Hh + th + hh);
        t[hh + 0][ww] = v4.x; t[hh + 1][ww] = v4.y;
        t[hh + 2][ww] = v4.z; t[hh + 3][ww] = v4.w;
    }
    __syncthreads();
    float g = gamma[0];
    int qw_ = threadIdx.x & 15;
    int qh_ = threadIdx.x >> 4;
    const float* yb = y_norm + (size_t)bc * PLANE;
    float* ob = out + (size_t)bc * PLANE;
    float mx = -1e30f;
    float2 res[2];
    #pragma unroll
    for (int i = 0; i < 2; ++i) {
        int hh = 2 * qh_ + i;
        int off = (th + hh) * Ww + tw + 2 * qw_;
        float2 v = *(const float2*)(ob + off);   // v_out lives in d_out
        float2 y = *(const float2*)(yb + off);
        float o0 = g * (t[hh][2 * qw_]     + v.x) + y.x;
        float o1 = g * (t[hh][2 * qw_ + 1] + v.y) + y.y;
        res[i] = make_float2(o0, o1);
        mx = fmaxf(mx, fmaxf(o0, o1));
    }
    #pragma unroll
    for (int i = 0; i < 2; ++i) {
        int off = (th + 2 * qh_ + i) * Ww + tw + 2 * qw_;
        *(float2*)(ob + off) = res[i];
    }
    down[(size_t)bc * 16384 + (th / 2 + qh_) * 128 + tw / 2 + qw_] = mx;
}

extern "C" void kernel_launch(void* const* d_in, const int* in_sizes, int n_in,
                              void* d_out, int out_size, void* d_ws, size_t ws_size,
                              hipStream_t stream)
{
    const float* x     = (const float*)d_in[0];
    const float* hw    = (const float*)d_in[1];
    const float* hb    = (const float*)d_in[2];
    const float* vw    = (const float*)d_in[3];
    const float* vb    = (const float*)d_in[4];
    const float* pww   = (const float*)d_in[5];
    const float* pwb   = (const float*)d_in[6];
    const float* bnw   = (const float*)d_in[7];
    const float* bnb   = (const float*)d_in[8];
    const float* qw    = (const float*)d_in[9];
    const float* qb    = (const float*)d_in[10];
    const float* kw    = (const float*)d_in[11];
    const float* kb    = (const float*)d_in[12];
    const float* vw2   = (const float*)d_in[13];
    const float* vb2   = (const float*)d_in[14];
    const float* gamma = (const float*)d_in[15];

    float* ws = (float*)d_ws;
    const size_t NP = (size_t)Bn * Cc * PLANE;          // 16,777,216
    const size_t NQ = (size_t)Bn * CQn * PLANE;         //  2,097,152
    float* y_raw  = ws;
    float* y_norm = ws + NP;
    float* valb   = ws + 2 * NP;
    float* qbuf   = ws + 3 * NP;
    float* kbuf   = qbuf + NQ;
    float* qT     = kbuf + NQ;
    float* kT     = qT + NQ;
    float* sums   = kT + NQ;
    float* sumsq  = sums + 256;
    float* alpha  = sums + 512;
    float* beta   = sums + 768;
    float* valT   = y_raw;   // reuse: y_raw dead after qkv
    float* houtT  = valb;    // reuse: valb dead after width attention
    float* out    = (float*)d_out;
    float* down   = out + NP;

    conv_pw_kernel<<<dim3(Bn * Hh), dim3(256), 0, stream>>>(
        x, hw, hb, vw, vb, pww, pwb, y_raw);
    stats_kernel<<<dim3(Bn * Cc), dim3(256), 0, stream>>>(y_raw, sums, sumsq);
    finalize_kernel<<<dim3(1), dim3(64), 0, stream>>>(sums, sumsq, bnw, bnb, alpha, beta);
    qkv_kernel<<<dim3(Bn * Hh), dim3(256), 0, stream>>>(
        y_raw, alpha, beta, qw, qb, kw, kb, vw2, vb2, y_norm, qbuf, kbuf, valb);
    transpose_kernel<<<dim3(Bn * CQn * 64), dim3(256), 0, stream>>>(qbuf, qT);
    transpose_kernel<<<dim3(Bn * CQn * 64), dim3(256), 0, stream>>>(kbuf, kT);
    // width attention: v_out -> d_out
    attn_kernel<<<dim3(Bn * Hh), dim3(256), 0, stream>>>(qbuf, kbuf, valb, out);
    // transpose val into y_raw's slot (y_raw dead), then height attention
    transpose_kernel<<<dim3(Bn * Cc * 64), dim3(256), 0, stream>>>(valb, valT);
    attn_kernel<<<dim3(Bn * Hh), dim3(256), 0, stream>>>(qT, kT, valT, houtT);
    final_kernel<<<dim3(Bn * Cc * 64), dim3(256), 0, stream>>>(
        houtT, y_norm, gamma, out, down);
}

// Round 2
// 1123.535 us; speedup vs baseline: 1.2099x; 1.2099x over previous
//
#include <hip/hip_runtime.h>

#define Bn 4
#define Cc 64
#define CQn 8
#define Hh 256
#define Ww 256
#define PLANE 65536

// ---------- Kernel 1a: axial depthwise conv + relu ----------
// grid: (b*64+c)*16 + htile ; block 256
__global__ __launch_bounds__(256) void dw_kernel(
    const float* __restrict__ x,
    const float* __restrict__ hw, const float* __restrict__ hb,
    const float* __restrict__ vw, const float* __restrict__ vb,
    float* __restrict__ aout)
{
    int blk = blockIdx.x;
    int bc = blk >> 4;
    int ht = blk & 15;
    int h0 = ht * 16;
    int c = bc & 63;
    int tid = threadIdx.x;
    __shared__ float rows[20][260];
    const float* xp = x + (size_t)bc * PLANE;
    #pragma unroll
    for (int i = 0; i < 20; ++i) {
        int hr = h0 - 2 + i;
        rows[i][tid + 2] = (hr >= 0 && hr < Hh) ? xp[hr * Ww + tid] : 0.f;
    }
    if (tid < 20) {
        rows[tid][0] = 0.f; rows[tid][1] = 0.f;
        rows[tid][258] = 0.f; rows[tid][259] = 0.f;
    }
    __syncthreads();

    float hw0 = hw[c * 5 + 0], hw1 = hw[c * 5 + 1], hw2 = hw[c * 5 + 2],
          hw3 = hw[c * 5 + 3], hw4 = hw[c * 5 + 4];
    float vw0 = vw[c * 5 + 0], vw1 = vw[c * 5 + 1], vw2 = vw[c * 5 + 2],
          vw3 = vw[c * 5 + 3], vw4 = vw[c * 5 + 4];
    float bias = hb[c] + vb[c];

    float* op = aout + (size_t)bc * PLANE + h0 * Ww + tid;
    #pragma unroll
    for (int r = 0; r < 16; ++r) {
        float hs = hw0 * rows[r + 2][tid]     + hw1 * rows[r + 2][tid + 1]
                 + hw2 * rows[r + 2][tid + 2] + hw3 * rows[r + 2][tid + 3]
                 + hw4 * rows[r + 2][tid + 4];
        float vs = vw0 * rows[r][tid + 2]     + vw1 * rows[r + 1][tid + 2]
                 + vw2 * rows[r + 2][tid + 2] + vw3 * rows[r + 3][tid + 2]
                 + vw4 * rows[r + 4][tid + 2];
        float res = hs + vs + bias + rows[r + 2][tid + 2];
        op[r * Ww] = fmaxf(res, 0.f);
    }
}

// ---------- Kernel 1b: pointwise 64x64 ----------
// grid: b*256 + pixel-tile ; block 256, one pixel per thread
__global__ __launch_bounds__(256) void pw_kernel(
    const float* __restrict__ a,
    const float* __restrict__ pww, const float* __restrict__ pwb,
    float* __restrict__ y_raw)
{
    int blk = blockIdx.x;
    int b = blk >> 8;
    int p = ((blk & 255) << 8) + threadIdx.x;
    size_t base = (size_t)b * Cc * PLANE + p;
    float yv[Cc];
    #pragma unroll
    for (int c = 0; c < Cc; ++c) yv[c] = a[base + (size_t)c * PLANE];
    for (int o = 0; o < Cc; ++o) {
        float acc = pwb[o];
        #pragma unroll
        for (int c = 0; c < Cc; ++c) acc += pww[o * Cc + c] * yv[c];
        y_raw[base + (size_t)o * PLANE] = acc;
    }
}

// ---------- Kernel 2: per-(b,c) quarter-plane sum / sumsq partials ----------
// grid: 4 segments x 256 planes
__global__ __launch_bounds__(256) void stats_kernel(
    const float* __restrict__ y, float* __restrict__ sums4, float* __restrict__ sumsq4)
{
    int blk = blockIdx.x;
    int bc = blk & 255;
    int seg = blk >> 8;
    const float* p = y + (size_t)bc * PLANE + seg * (PLANE / 4);
    float s = 0.f, s2 = 0.f;
    for (int i = threadIdx.x; i < PLANE / 4; i += 256) {
        float v = p[i];
        s += v; s2 += v * v;
    }
    #pragma unroll
    for (int off = 32; off > 0; off >>= 1) {
        s  += __shfl_down(s, off);
        s2 += __shfl_down(s2, off);
    }
    __shared__ float red[8];
    int lane = threadIdx.x & 63, wv = threadIdx.x >> 6;
    if (lane == 0) { red[wv] = s; red[4 + wv] = s2; }
    __syncthreads();
    if (threadIdx.x == 0) {
        float a = 0.f, b2 = 0.f;
        for (int i = 0; i < 4; ++i) { a += red[i]; b2 += red[4 + i]; }
        sums4[seg * 256 + bc] = a; sumsq4[seg * 256 + bc] = b2;
    }
}

// ---------- Kernel 3: fold hybrid norm into per-(b,c) affine ----------
__global__ void finalize_kernel(
    const float* __restrict__ sums4, const float* __restrict__ sumsq4,
    const float* __restrict__ bn_w, const float* __restrict__ bn_b,
    float* __restrict__ alpha, float* __restrict__ beta)
{
    int c = threadIdx.x;
    if (c >= Cc) return;
    float im[4], e2[4];
    float bm = 0.f, be2 = 0.f;
    for (int b = 0; b < 4; ++b) {
        float s = 0.f, s2 = 0.f;
        for (int seg = 0; seg < 4; ++seg) {
            s  += sums4[seg * 256 + b * Cc + c];
            s2 += sumsq4[seg * 256 + b * Cc + c];
        }
        im[b] = s * (1.f / 65536.f);
        e2[b] = s2 * (1.f / 65536.f);
        bm += im[b]; be2 += e2[b];
    }
    bm *= 0.25f; be2 *= 0.25f;
    float bv = be2 - bm * bm;
    float rsb = rsqrtf(bv + 1e-5f);
    float wgt = bn_w[c], bb = bn_b[c];
    for (int b = 0; b < 4; ++b) {
        float iv = e2[b] - im[b] * im[b];
        float rsi = rsqrtf(iv + 1e-5f);
        float al = 0.7f * rsi + 0.3f * rsb * wgt;
        float bt = -0.7f * im[b] * rsi - 0.3f * bm * rsb * wgt + 0.3f * bb;
        alpha[b * Cc + c] = al;
        beta[b * Cc + c] = bt;
    }
}

// ---------- Kernel 4: normalize + q/k/v projections ----------
__global__ __launch_bounds__(256) void qkv_kernel(
    const float* __restrict__ y_raw,
    const float* __restrict__ alpha, const float* __restrict__ beta,
    const float* __restrict__ qw, const float* __restrict__ qbias,
    const float* __restrict__ kw, const float* __restrict__ kbias,
    const float* __restrict__ vw, const float* __restrict__ vbias,
    float* __restrict__ y_norm, float* __restrict__ q, float* __restrict__ k,
    float* __restrict__ val)
{
    int blk = blockIdx.x;
    int b = blk >> 8;
    int h = blk & 255;
    int w = threadIdx.x;
    size_t base = (size_t)b * Cc * PLANE + h * Ww + w;
    float y[Cc];
    #pragma unroll
    for (int c = 0; c < Cc; ++c) {
        float v = y_raw[base + (size_t)c * PLANE];
        v = alpha[b * Cc + c] * v + beta[b * Cc + c];
        y[c] = v;
        y_norm[base + (size_t)c * PLANE] = v;
    }
    size_t qbase = (size_t)b * CQn * PLANE + h * Ww + w;
    for (int o = 0; o < CQn; ++o) {
        float aq = qbias[o], ak = kbias[o];
        #pragma unroll
        for (int c = 0; c < Cc; ++c) {
            aq += qw[o * Cc + c] * y[c];
            ak += kw[o * Cc + c] * y[c];
        }
        q[qbase + (size_t)o * PLANE] = aq;
        k[qbase + (size_t)o * PLANE] = ak;
    }
    for (int o = 0; o < Cc; ++o) {
        float av = vbias[o];
        #pragma unroll
        for (int c = 0; c < Cc; ++c) av += vw[o * Cc + c] * y[c];
        val[base + (size_t)o * PLANE] = av;
    }
}

// ---------- Kernel 5: batched 256x256 plane transpose ----------
__global__ __launch_bounds__(256) void transpose_kernel(
    const float* __restrict__ src, float* __restrict__ dst)
{
    int blk = blockIdx.x;
    int plane = blk >> 6;
    int tile = blk & 63;
    int th = (tile >> 3) * 32;
    int tw = (tile & 7) * 32;
    __shared__ float t[32][33];
    const float* s = src + (size_t)plane * PLANE;
    float* d = dst + (size_t)plane * PLANE;
    int lw = threadIdx.x & 31;
    int lh = threadIdx.x >> 5;  // 0..7
    #pragma unroll
    for (int i = 0; i < 4; ++i)
        t[lh + 8 * i][lw] = s[(th + lh + 8 * i) * Ww + tw + lw];
    __syncthreads();
    #pragma unroll
    for (int i = 0; i < 4; ++i)
        d[(tw + lh + 8 * i) * Hh + th + lw] = t[lw][lh + 8 * i];
}

// ---------- Kernel 6: generic row attention (softmax over last axis keys) ----------
__global__ __launch_bounds__(256) void attn_kernel(
    const float* __restrict__ q, const float* __restrict__ k,
    const float* __restrict__ val, float* __restrict__ out)
{
    int blk = blockIdx.x;
    int b = blk >> 8;
    int r = blk & 255;
    int tid = threadIdx.x;
    __shared__ float qs[256][8];
    __shared__ float ks[256][8];
    __shared__ float vs[256][68];
    __shared__ float mlb[256][2];

    size_t qbase = (size_t)b * CQn * PLANE + (size_t)r * Ww;
    float qreg[8], kreg[8];
    #pragma unroll
    for (int c = 0; c < 8; ++c) {
        float qv = q[qbase + (size_t)c * PLANE + tid];
        float kv = k[qbase + (size_t)c * PLANE + tid];
        qs[tid][c] = qv; ks[tid][c] = kv;
        qreg[c] = qv; kreg[c] = kv;
    }
    size_t vbase = (size_t)b * Cc * PLANE + (size_t)r * Ww;
    #pragma unroll 8
    for (int c = 0; c < Cc; ++c) vs[tid][c] = val[vbase + (size_t)c * PLANE + tid];
    __syncthreads();

    float m = -1e30f, l = 0.f;
    for (int i = 0; i < 256; ++i) {
        float s = 0.f;
        #pragma unroll
        for (int c = 0; c < 8; ++c) s += qreg[c] * ks[i][c];
        float nm = fmaxf(m, s);
        l = l * __expf(m - nm) + __expf(s - nm);
        m = nm;
    }
    mlb[tid][0] = m;
    mlb[tid][1] = 1.f / l;
    __syncthreads();

    float acc[Cc];
    #pragma unroll
    for (int c = 0; c < Cc; ++c) acc[c] = 0.f;
    for (int j = 0; j < 256; ++j) {
        float s = 0.f;
        #pragma unroll
        for (int c = 0; c < 8; ++c) s += qs[j][c] * kreg[c];
        float aw = __expf(s - mlb[j][0]) * mlb[j][1];
        #pragma unroll
        for (int c = 0; c < Cc; ++c) acc[c] += aw * vs[j][c];
    }
    #pragma unroll
    for (int c = 0; c < Cc; ++c) out[vbase + (size_t)c * PLANE + tid] = acc[c];
}

// ---------- Kernel 7: combine + residual + 2x2 maxpool ----------
__global__ __launch_bounds__(256) void final_kernel(
    const float* __restrict__ houtT, const float* __restrict__ y_norm,
    const float* __restrict__ gamma,
    float* __restrict__ out, float* __restrict__ down)
{
    int blk = blockIdx.x;
    int tile = blk & 63;
    int bc = blk >> 6;
    int th = (tile >> 3) * 32;
    int tw = (tile & 7) * 32;
    __shared__ float t[32][33];
    const float* hT = houtT + (size_t)bc * PLANE;
    {
        int ww = threadIdx.x >> 3;
        int hh = (threadIdx.x & 7) * 4;
        const float4 v4 = *(const float4*)(hT + (size_t)(tw + ww) * Hh + th + hh);
        t[hh + 0][ww] = v4.x; t[hh + 1][ww] = v4.y;
        t[hh + 2][ww] = v4.z; t[hh + 3][ww] = v4.w;
    }
    __syncthreads();
    float g = gamma[0];
    int qw_ = threadIdx.x & 15;
    int qh_ = threadIdx.x >> 4;
    const float* yb = y_norm + (size_t)bc * PLANE;
    float* ob = out + (size_t)bc * PLANE;
    float mx = -1e30f;
    float2 res[2];
    #pragma unroll
    for (int i = 0; i < 2; ++i) {
        int hh = 2 * qh_ + i;
        int off = (th + hh) * Ww + tw + 2 * qw_;
        float2 v = *(const float2*)(ob + off);
        float2 y = *(const float2*)(yb + off);
        float o0 = g * (t[hh][2 * qw_]     + v.x) + y.x;
        float o1 = g * (t[hh][2 * qw_ + 1] + v.y) + y.y;
        res[i] = make_float2(o0, o1);
        mx = fmaxf(mx, fmaxf(o0, o1));
    }
    #pragma unroll
    for (int i = 0; i < 2; ++i) {
        int off = (th + 2 * qh_ + i) * Ww + tw + 2 * qw_;
        *(float2*)(ob + off) = res[i];
    }
    down[(size_t)bc * 16384 + (th / 2 + qh_) * 128 + tw / 2 + qw_] = mx;
}

extern "C" void kernel_launch(void* const* d_in, const int* in_sizes, int n_in,
                              void* d_out, int out_size, void* d_ws, size_t ws_size,
                              hipStream_t stream)
{
    const float* x     = (const float*)d_in[0];
    const float* hw    = (const float*)d_in[1];
    const float* hb    = (const float*)d_in[2];
    const float* vw    = (const float*)d_in[3];
    const float* vb    = (const float*)d_in[4];
    const float* pww   = (const float*)d_in[5];
    const float* pwb   = (const float*)d_in[6];
    const float* bnw   = (const float*)d_in[7];
    const float* bnb   = (const float*)d_in[8];
    const float* qw    = (const float*)d_in[9];
    const float* qb    = (const float*)d_in[10];
    const float* kw    = (const float*)d_in[11];
    const float* kb    = (const float*)d_in[12];
    const float* vw2   = (const float*)d_in[13];
    const float* vb2   = (const float*)d_in[14];
    const float* gamma = (const float*)d_in[15];

    float* ws = (float*)d_ws;
    const size_t NP = (size_t)Bn * Cc * PLANE;
    const size_t NQ = (size_t)Bn * CQn * PLANE;
    float* y_raw  = ws;            // slot A
    float* slotB  = ws + NP;       // a_buf (dw->pw), then y_norm (qkv onward)
    float* valb   = ws + 2 * NP;
    float* qbuf   = ws + 3 * NP;
    float* kbuf   = qbuf + NQ;
    float* qT     = kbuf + NQ;
    float* kT     = qT + NQ;
    float* sums4  = kT + NQ;       // 1024
    float* sumsq4 = sums4 + 1024;  // 1024
    float* alpha  = sumsq4 + 1024; // 256
    float* beta   = alpha + 256;   // 256
    float* a_buf  = slotB;
    float* y_norm = slotB;
    float* valT   = y_raw;   // reuse: y_raw dead after qkv
    float* houtT  = valb;    // reuse: valb dead after width attention
    float* out    = (float*)d_out;
    float* down   = out + NP;

    dw_kernel<<<dim3(Bn * Cc * 16), dim3(256), 0, stream>>>(
        x, hw, hb, vw, vb, a_buf);
    pw_kernel<<<dim3(Bn * 256), dim3(256), 0, stream>>>(a_buf, pww, pwb, y_raw);
    stats_kernel<<<dim3(4 * 256), dim3(256), 0, stream>>>(y_raw, sums4, sumsq4);
    finalize_kernel<<<dim3(1), dim3(64), 0, stream>>>(sums4, sumsq4, bnw, bnb, alpha, beta);
    qkv_kernel<<<dim3(Bn * Hh), dim3(256), 0, stream>>>(
        y_raw, alpha, beta, qw, qb, kw, kb, vw2, vb2, y_norm, qbuf, kbuf, valb);
    transpose_kernel<<<dim3(Bn * CQn * 64), dim3(256), 0, stream>>>(qbuf, qT);
    transpose_kernel<<<dim3(Bn * CQn * 64), dim3(256), 0, stream>>>(kbuf, kT);
    attn_kernel<<<dim3(Bn * Hh), dim3(256), 0, stream>>>(qbuf, kbuf, valb, out);
    transpose_kernel<<<dim3(Bn * Cc * 64), dim3(256), 0, stream>>>(valb, valT);
    attn_kernel<<<dim3(Bn * Hh), dim3(256), 0, stream>>>(qT, kT, valT, houtT);
    final_kernel<<<dim3(Bn * Cc * 64), dim3(256), 0, stream>>>(
        houtT, y_norm, gamma, out, down);
}

// Round 3
// 737.030 us; speedup vs baseline: 1.8444x; 1.5244x over previous
//
#include <hip/hip_runtime.h>
#include <hip/hip_bf16.h>

#define Bn 4
#define Cc 64
#define CQn 8
#define Hh 256
#define Ww 256
#define PLANE 65536

typedef unsigned short ushortT;
typedef __attribute__((ext_vector_type(8))) unsigned short us8;
typedef __attribute__((ext_vector_type(4))) unsigned short us4;
typedef __attribute__((ext_vector_type(8))) __bf16 bf16x8;
typedef __attribute__((ext_vector_type(4))) float f32x4;

// ---------- Kernel 1a: axial depthwise conv + relu ----------
__global__ __launch_bounds__(256) void dw_kernel(
    const float* __restrict__ x,
    const float* __restrict__ hw, const float* __restrict__ hb,
    const float* __restrict__ vw, const float* __restrict__ vb,
    float* __restrict__ aout)
{
    int blk = blockIdx.x;
    int bc = blk >> 4;
    int ht = blk & 15;
    int h0 = ht * 16;
    int c = bc & 63;
    int tid = threadIdx.x;
    __shared__ float rows[20][260];
    const float* xp = x + (size_t)bc * PLANE;
    #pragma unroll
    for (int i = 0; i < 20; ++i) {
        int hr = h0 - 2 + i;
        rows[i][tid + 2] = (hr >= 0 && hr < Hh) ? xp[hr * Ww + tid] : 0.f;
    }
    if (tid < 20) {
        rows[tid][0] = 0.f; rows[tid][1] = 0.f;
        rows[tid][258] = 0.f; rows[tid][259] = 0.f;
    }
    __syncthreads();

    float hw0 = hw[c * 5 + 0], hw1 = hw[c * 5 + 1], hw2 = hw[c * 5 + 2],
          hw3 = hw[c * 5 + 3], hw4 = hw[c * 5 + 4];
    float vw0 = vw[c * 5 + 0], vw1 = vw[c * 5 + 1], vw2 = vw[c * 5 + 2],
          vw3 = vw[c * 5 + 3], vw4 = vw[c * 5 + 4];
    float bias = hb[c] + vb[c];

    float* op = aout + (size_t)bc * PLANE + h0 * Ww + tid;
    #pragma unroll
    for (int r = 0; r < 16; ++r) {
        float hs = hw0 * rows[r + 2][tid]     + hw1 * rows[r + 2][tid + 1]
                 + hw2 * rows[r + 2][tid + 2] + hw3 * rows[r + 2][tid + 3]
                 + hw4 * rows[r + 2][tid + 4];
        float vs = vw0 * rows[r][tid + 2]     + vw1 * rows[r + 1][tid + 2]
                 + vw2 * rows[r + 2][tid + 2] + vw3 * rows[r + 3][tid + 2]
                 + vw4 * rows[r + 4][tid + 2];
        float res = hs + vs + bias + rows[r + 2][tid + 2];
        op[r * Ww] = fmaxf(res, 0.f);
    }
}

// ---------- Kernel 1b: pointwise 64x64 ----------
__global__ __launch_bounds__(256) void pw_kernel(
    const float* __restrict__ a,
    const float* __restrict__ pww, const float* __restrict__ pwb,
    float* __restrict__ y_raw)
{
    int blk = blockIdx.x;
    int b = blk >> 8;
    int p = ((blk & 255) << 8) + threadIdx.x;
    size_t base = (size_t)b * Cc * PLANE + p;
    float yv[Cc];
    #pragma unroll
    for (int c = 0; c < Cc; ++c) yv[c] = a[base + (size_t)c * PLANE];
    for (int o = 0; o < Cc; ++o) {
        float acc = pwb[o];
        #pragma unroll
        for (int c = 0; c < Cc; ++c) acc += pww[o * Cc + c] * yv[c];
        y_raw[base + (size_t)o * PLANE] = acc;
    }
}

// ---------- Kernel 2: per-(b,c) quarter-plane sum / sumsq partials ----------
__global__ __launch_bounds__(256) void stats_kernel(
    const float* __restrict__ y, float* __restrict__ sums4, float* __restrict__ sumsq4)
{
    int blk = blockIdx.x;
    int bc = blk & 255;
    int seg = blk >> 8;
    const float* p = y + (size_t)bc * PLANE + seg * (PLANE / 4);
    float s = 0.f, s2 = 0.f;
    for (int i = threadIdx.x; i < PLANE / 4; i += 256) {
        float v = p[i];
        s += v; s2 += v * v;
    }
    #pragma unroll
    for (int off = 32; off > 0; off >>= 1) {
        s  += __shfl_down(s, off);
        s2 += __shfl_down(s2, off);
    }
    __shared__ float red[8];
    int lane = threadIdx.x & 63, wv = threadIdx.x >> 6;
    if (lane == 0) { red[wv] = s; red[4 + wv] = s2; }
    __syncthreads();
    if (threadIdx.x == 0) {
        float a = 0.f, b2 = 0.f;
        for (int i = 0; i < 4; ++i) { a += red[i]; b2 += red[4 + i]; }
        sums4[seg * 256 + bc] = a; sumsq4[seg * 256 + bc] = b2;
    }
}

// ---------- Kernel 3: fold hybrid norm into per-(b,c) affine ----------
__global__ void finalize_kernel(
    const float* __restrict__ sums4, const float* __restrict__ sumsq4,
    const float* __restrict__ bn_w, const float* __restrict__ bn_b,
    float* __restrict__ alpha, float* __restrict__ beta)
{
    int c = threadIdx.x;
    if (c >= Cc) return;
    float im[4], e2[4];
    float bm = 0.f, be2 = 0.f;
    for (int b = 0; b < 4; ++b) {
        float s = 0.f, s2 = 0.f;
        for (int seg = 0; seg < 4; ++seg) {
            s  += sums4[seg * 256 + b * Cc + c];
            s2 += sumsq4[seg * 256 + b * Cc + c];
        }
        im[b] = s * (1.f / 65536.f);
        e2[b] = s2 * (1.f / 65536.f);
        bm += im[b]; be2 += e2[b];
    }
    bm *= 0.25f; be2 *= 0.25f;
    float bv = be2 - bm * bm;
    float rsb = rsqrtf(bv + 1e-5f);
    float wgt = bn_w[c], bb = bn_b[c];
    for (int b = 0; b < 4; ++b) {
        float iv = e2[b] - im[b] * im[b];
        float rsi = rsqrtf(iv + 1e-5f);
        float al = 0.7f * rsi + 0.3f * rsb * wgt;
        float bt = -0.7f * im[b] * rsi - 0.3f * bm * rsb * wgt + 0.3f * bb;
        alpha[b * Cc + c] = al;
        beta[b * Cc + c] = bt;
    }
}

// ---------- Kernel 4: normalize + q/k/v projections (val -> bf16) ----------
__global__ __launch_bounds__(256) void qkv_kernel(
    const float* __restrict__ y_raw,
    const float* __restrict__ alpha, const float* __restrict__ beta,
    const float* __restrict__ qw, const float* __restrict__ qbias,
    const float* __restrict__ kw, const float* __restrict__ kbias,
    const float* __restrict__ vw, const float* __restrict__ vbias,
    float* __restrict__ y_norm, float* __restrict__ q, float* __restrict__ k,
    __hip_bfloat16* __restrict__ val)
{
    int blk = blockIdx.x;
    int b = blk >> 8;
    int h = blk & 255;
    int w = threadIdx.x;
    size_t base = (size_t)b * Cc * PLANE + h * Ww + w;
    float y[Cc];
    #pragma unroll
    for (int c = 0; c < Cc; ++c) {
        float v = y_raw[base + (size_t)c * PLANE];
        v = alpha[b * Cc + c] * v + beta[b * Cc + c];
        y[c] = v;
        y_norm[base + (size_t)c * PLANE] = v;
    }
    size_t qbase = (size_t)b * CQn * PLANE + h * Ww + w;
    for (int o = 0; o < CQn; ++o) {
        float aq = qbias[o], ak = kbias[o];
        #pragma unroll
        for (int c = 0; c < Cc; ++c) {
            aq += qw[o * Cc + c] * y[c];
            ak += kw[o * Cc + c] * y[c];
        }
        q[qbase + (size_t)o * PLANE] = aq;
        k[qbase + (size_t)o * PLANE] = ak;
    }
    for (int o = 0; o < Cc; ++o) {
        float av = vbias[o];
        #pragma unroll
        for (int c = 0; c < Cc; ++c) av += vw[o * Cc + c] * y[c];
        val[base + (size_t)o * PLANE] = __float2bfloat16(av);
    }
}

// ---------- Kernel 5a: batched 256x256 fp32 plane transpose ----------
__global__ __launch_bounds__(256) void transpose_kernel(
    const float* __restrict__ src, float* __restrict__ dst)
{
    int blk = blockIdx.x;
    int plane = blk >> 6;
    int tile = blk & 63;
    int th = (tile >> 3) * 32;
    int tw = (tile & 7) * 32;
    __shared__ float t[32][33];
    const float* s = src + (size_t)plane * PLANE;
    float* d = dst + (size_t)plane * PLANE;
    int lw = threadIdx.x & 31;
    int lh = threadIdx.x >> 5;
    #pragma unroll
    for (int i = 0; i < 4; ++i)
        t[lh + 8 * i][lw] = s[(th + lh + 8 * i) * Ww + tw + lw];
    __syncthreads();
    #pragma unroll
    for (int i = 0; i < 4; ++i)
        d[(tw + lh + 8 * i) * Hh + th + lw] = t[lw][lh + 8 * i];
}

// ---------- Kernel 5b: batched 256x256 bf16 plane transpose ----------
__global__ __launch_bounds__(256) void transpose16_kernel(
    const ushortT* __restrict__ src, ushortT* __restrict__ dst)
{
    int blk = blockIdx.x;
    int plane = blk >> 6;
    int tile = blk & 63;
    int th = (tile >> 3) * 32;
    int tw = (tile & 7) * 32;
    __shared__ ushortT t[32][34];
    const ushortT* s = src + (size_t)plane * PLANE;
    ushortT* d = dst + (size_t)plane * PLANE;
    int lw = threadIdx.x & 31;
    int lh = threadIdx.x >> 5;
    #pragma unroll
    for (int i = 0; i < 4; ++i)
        t[lh + 8 * i][lw] = s[(th + lh + 8 * i) * Ww + tw + lw];
    __syncthreads();
    #pragma unroll
    for (int i = 0; i < 4; ++i)
        d[(tw + lh + 8 * i) * Hh + th + lw] = t[lw][lh + 8 * i];
}

// ---------- Kernel 6: MFMA row attention ----------
// Per block = one (b, row): fp32 softmax stats, then 8 K-steps of
// [compute 32xj slab of A in bf16 -> LDS] x [mfma 4 c-tiles x 16 i-tiles].
template<bool BF16OUT>
__global__ __launch_bounds__(256) void attn_mfma_kernel(
    const float* __restrict__ q, const float* __restrict__ k,
    const ushortT* __restrict__ val, void* __restrict__ outp)
{
    int blk = blockIdx.x;
    int b = blk >> 8;
    int r = blk & 255;
    int tid = threadIdx.x;
    int lane = tid & 63;
    int wv = tid >> 6;

    __shared__ ushortT val_lds[64 * 264];   // [c][i], pad 264
    __shared__ ushortT A_lds[256 * 40];     // [i][j-slab of 32], pad 40
    __shared__ float qsh[256 * 8];
    __shared__ float ksh[256 * 8];
    __shared__ float mlb[256 * 2];

    // stage q, k (fp32)
    size_t qbase = (size_t)b * CQn * PLANE + (size_t)r * Ww;
    float qreg[8], kreg[8];
    #pragma unroll
    for (int c = 0; c < 8; ++c) {
        float qv = q[qbase + (size_t)c * PLANE + tid];
        float kv = k[qbase + (size_t)c * PLANE + tid];
        qsh[tid * 8 + c] = qv; ksh[tid * 8 + c] = kv;
        qreg[c] = qv; kreg[c] = kv;
    }
    // stage val (bf16): 8 passes of 8 rows
    size_t vbase = (size_t)b * Cc * PLANE + (size_t)r * Ww;
    {
        int crow = tid >> 5;       // 0..7
        int chunk = tid & 31;      // 16B chunks
        #pragma unroll
        for (int pass = 0; pass < 8; ++pass) {
            int c = pass * 8 + crow;
            us8 v = *(const us8*)(val + vbase + (size_t)c * PLANE + chunk * 8);
            *(us8*)&val_lds[c * 264 + chunk * 8] = v;
        }
    }
    __syncthreads();

    // phase 1: thread = query j, online softmax over keys i
    float m = -1e30f, l = 0.f;
    for (int i = 0; i < 256; ++i) {
        const float* kr = &ksh[i * 8];
        float s = qreg[0] * kr[0] + qreg[1] * kr[1] + qreg[2] * kr[2] + qreg[3] * kr[3]
                + qreg[4] * kr[4] + qreg[5] * kr[5] + qreg[6] * kr[6] + qreg[7] * kr[7];
        float nm = fmaxf(m, s);
        l = l * __expf(m - nm) + __expf(s - nm);
        m = nm;
    }
    mlb[tid * 2 + 0] = m;
    mlb[tid * 2 + 1] = 1.f / l;
    __syncthreads();

    // phase 2: 8 K-steps
    f32x4 acc[16];
    #pragma unroll
    for (int t = 0; t < 16; ++t) acc[t] = (f32x4){0.f, 0.f, 0.f, 0.f};

    for (int ks = 0; ks < 8; ++ks) {
        int j0 = ks * 32;
        // thread = column i: compute A[j0..j0+31][i] in bf16
        #pragma unroll
        for (int chunk = 0; chunk < 4; ++chunk) {
            bf16x8 pk;
            #pragma unroll
            for (int jj = 0; jj < 8; ++jj) {
                int j = j0 + chunk * 8 + jj;
                const float* qr = &qsh[j * 8];
                float s = qr[0] * kreg[0] + qr[1] * kreg[1] + qr[2] * kreg[2] + qr[3] * kreg[3]
                        + qr[4] * kreg[4] + qr[5] * kreg[5] + qr[6] * kreg[6] + qr[7] * kreg[7];
                float aw = __expf(s - mlb[j * 2 + 0]) * mlb[j * 2 + 1];
                pk[jj] = (__bf16)aw;
            }
            *(bf16x8*)&A_lds[tid * 40 + chunk * 8] = pk;
        }
        __syncthreads();
        // MFMA: wave wv owns c-tile wv; sweep 16 i-tiles
        bf16x8 af = *(const bf16x8*)&val_lds[(wv * 16 + (lane & 15)) * 264 + j0 + (lane >> 4) * 8];
        #pragma unroll
        for (int t = 0; t < 16; ++t) {
            bf16x8 bf = *(const bf16x8*)&A_lds[(t * 16 + (lane & 15)) * 40 + (lane >> 4) * 8];
            acc[t] = __builtin_amdgcn_mfma_f32_16x16x32_bf16(af, bf, acc[t], 0, 0, 0);
        }
        __syncthreads();
    }

    // store: C/D layout col=lane&15, row=(lane>>4)*4+reg
    size_t obase = (size_t)b * Cc * PLANE + (size_t)r * Ww;
    #pragma unroll
    for (int t = 0; t < 16; ++t) {
        int i = t * 16 + (lane & 15);
        #pragma unroll
        for (int rr = 0; rr < 4; ++rr) {
            int c = wv * 16 + (lane >> 4) * 4 + rr;
            float v = acc[t][rr];
            size_t addr = obase + (size_t)c * PLANE + i;
            if (BF16OUT) ((__hip_bfloat16*)outp)[addr] = __float2bfloat16(v);
            else         ((float*)outp)[addr] = v;
        }
    }
}

// ---------- Kernel 7: combine + residual + 2x2 maxpool ----------
__global__ __launch_bounds__(256) void final_kernel(
    const ushortT* __restrict__ houtT, const float* __restrict__ y_norm,
    const float* __restrict__ gamma,
    float* __restrict__ out, float* __restrict__ down)
{
    int blk = blockIdx.x;
    int tile = blk & 63;
    int bc = blk >> 6;
    int th = (tile >> 3) * 32;
    int tw = (tile & 7) * 32;
    __shared__ float t[32][33];
    const ushortT* hT = houtT + (size_t)bc * PLANE;
    {
        int ww = threadIdx.x >> 3;
        int hh = (threadIdx.x & 7) * 4;
        us4 v4 = *(const us4*)(hT + (size_t)(tw + ww) * Hh + th + hh);
        t[hh + 0][ww] = __uint_as_float((unsigned)v4[0] << 16);
        t[hh + 1][ww] = __uint_as_float((unsigned)v4[1] << 16);
        t[hh + 2][ww] = __uint_as_float((unsigned)v4[2] << 16);
        t[hh + 3][ww] = __uint_as_float((unsigned)v4[3] << 16);
    }
    __syncthreads();
    float g = gamma[0];
    int qw_ = threadIdx.x & 15;
    int qh_ = threadIdx.x >> 4;
    const float* yb = y_norm + (size_t)bc * PLANE;
    float* ob = out + (size_t)bc * PLANE;
    float mx = -1e30f;
    float2 res[2];
    #pragma unroll
    for (int i = 0; i < 2; ++i) {
        int hh = 2 * qh_ + i;
        int off = (th + hh) * Ww + tw + 2 * qw_;
        float2 v = *(const float2*)(ob + off);
        float2 y = *(const float2*)(yb + off);
        float o0 = g * (t[hh][2 * qw_]     + v.x) + y.x;
        float o1 = g * (t[hh][2 * qw_ + 1] + v.y) + y.y;
        res[i] = make_float2(o0, o1);
        mx = fmaxf(mx, fmaxf(o0, o1));
    }
    #pragma unroll
    for (int i = 0; i < 2; ++i) {
        int off = (th + 2 * qh_ + i) * Ww + tw + 2 * qw_;
        *(float2*)(ob + off) = res[i];
    }
    down[(size_t)bc * 16384 + (th / 2 + qh_) * 128 + tw / 2 + qw_] = mx;
}

extern "C" void kernel_launch(void* const* d_in, const int* in_sizes, int n_in,
                              void* d_out, int out_size, void* d_ws, size_t ws_size,
                              hipStream_t stream)
{
    const float* x     = (const float*)d_in[0];
    const float* hw    = (const float*)d_in[1];
    const float* hb    = (const float*)d_in[2];
    const float* vw    = (const float*)d_in[3];
    const float* vb    = (const float*)d_in[4];
    const float* pww   = (const float*)d_in[5];
    const float* pwb   = (const float*)d_in[6];
    const float* bnw   = (const float*)d_in[7];
    const float* bnb   = (const float*)d_in[8];
    const float* qw    = (const float*)d_in[9];
    const float* qb    = (const float*)d_in[10];
    const float* kw    = (const float*)d_in[11];
    const float* kb    = (const float*)d_in[12];
    const float* vw2   = (const float*)d_in[13];
    const float* vb2   = (const float*)d_in[14];
    const float* gamma = (const float*)d_in[15];

    float* ws = (float*)d_ws;
    const size_t NP = (size_t)Bn * Cc * PLANE;   // 16.7M elems
    const size_t NQ = (size_t)Bn * CQn * PLANE;  // 2.1M elems
    float* y_raw  = ws;                // [NP] ; later valT (ushort, NP elems = NP/2 floats)
    float* slotB  = ws + NP;           // a_buf then y_norm
    float* valb_f = ws + 2 * NP;       // [NP/2 floats] = NP bf16 ; later houtT (bf16)
    float* qbuf   = ws + 2 * NP + NP / 2;
    float* kbuf   = qbuf + NQ;
    float* qT     = kbuf + NQ;
    float* kT     = qT + NQ;
    float* sums4  = kT + NQ;
    float* sumsq4 = sums4 + 1024;
    float* alpha  = sumsq4 + 1024;
    float* beta   = alpha + 256;

    float* a_buf  = slotB;
    float* y_norm = slotB;
    ushortT* valb  = (ushortT*)valb_f;
    ushortT* valT  = (ushortT*)y_raw;     // y_raw dead after qkv
    ushortT* houtT = (ushortT*)valb_f;    // valb dead after width attn
    float* out    = (float*)d_out;
    float* down   = out + NP;

    dw_kernel<<<dim3(Bn * Cc * 16), dim3(256), 0, stream>>>(
        x, hw, hb, vw, vb, a_buf);
    pw_kernel<<<dim3(Bn * 256), dim3(256), 0, stream>>>(a_buf, pww, pwb, y_raw);
    stats_kernel<<<dim3(4 * 256), dim3(256), 0, stream>>>(y_raw, sums4, sumsq4);
    finalize_kernel<<<dim3(1), dim3(64), 0, stream>>>(sums4, sumsq4, bnw, bnb, alpha, beta);
    qkv_kernel<<<dim3(Bn * Hh), dim3(256), 0, stream>>>(
        y_raw, alpha, beta, qw, qb, kw, kb, vw2, vb2, y_norm, qbuf, kbuf,
        (__hip_bfloat16*)valb);
    transpose_kernel<<<dim3(Bn * CQn * 64), dim3(256), 0, stream>>>(qbuf, qT);
    transpose_kernel<<<dim3(Bn * CQn * 64), dim3(256), 0, stream>>>(kbuf, kT);
    transpose16_kernel<<<dim3(Bn * Cc * 64), dim3(256), 0, stream>>>(valb, valT);
    // width attention -> fp32 into d_out
    attn_mfma_kernel<false><<<dim3(Bn * Hh), dim3(256), 0, stream>>>(
        qbuf, kbuf, valb, (void*)out);
    // height attention -> bf16 into houtT (aliases valb, dead by now)
    attn_mfma_kernel<true><<<dim3(Bn * Hh), dim3(256), 0, stream>>>(
        qT, kT, valT, (void*)houtT);
    final_kernel<<<dim3(Bn * Cc * 64), dim3(256), 0, stream>>>(
        houtT, y_norm, gamma, out, down);
}

// Round 4
// 524.629 us; speedup vs baseline: 2.5911x; 1.4049x over previous
//
#include <hip/hip_runtime.h>
#include <hip/hip_bf16.h>

#define Bn 4
#define Cc 64
#define CQn 8
#define Hh 256
#define Ww 256
#define PLANE 65536

typedef unsigned short ushortT;
typedef __attribute__((ext_vector_type(8))) unsigned short us8;
typedef __attribute__((ext_vector_type(4))) unsigned short us4;
typedef __attribute__((ext_vector_type(8))) __bf16 bf16x8;
typedef __attribute__((ext_vector_type(4))) float f32x4;

__device__ inline ushortT f2bf(float f) {
    __hip_bfloat16 h = __float2bfloat16(f);
    return *(ushortT*)&h;
}
union BF8U { us8 u; bf16x8 b; uint4 w; };

// ---------- Kernel 0: pack weights to bf16 ----------
// pw_bf[64][64], qk_bf[16][64] (q rows 0-7, k rows 8-15), vw_bf[64][64]
__global__ void pack_weights_kernel(
    const float* __restrict__ pww, const float* __restrict__ qw,
    const float* __restrict__ kw, const float* __restrict__ vw,
    ushortT* __restrict__ pw_bf, ushortT* __restrict__ qk_bf,
    ushortT* __restrict__ vw_bf)
{
    int i = blockIdx.x * 256 + threadIdx.x;
    if (i < 64 * 64) pw_bf[i] = f2bf(pww[i]);
    if (i < 64 * 64) vw_bf[i] = f2bf(vw[i]);
    if (i < 8 * 64)  qk_bf[i] = f2bf(qw[i]);
    if (i >= 8 * 64 && i < 16 * 64) qk_bf[i] = f2bf(kw[i - 512]);
}

// ---------- Kernel 1a: axial depthwise conv + relu (bf16 out) ----------
__global__ __launch_bounds__(256) void dw_kernel(
    const float* __restrict__ x,
    const float* __restrict__ hw, const float* __restrict__ hb,
    const float* __restrict__ vw, const float* __restrict__ vb,
    ushortT* __restrict__ aout)
{
    int blk = blockIdx.x;
    int bc = blk >> 4;
    int ht = blk & 15;
    int h0 = ht * 16;
    int c = bc & 63;
    int tid = threadIdx.x;
    __shared__ float rows[20][260];
    const float* xp = x + (size_t)bc * PLANE;
    #pragma unroll
    for (int i = 0; i < 20; ++i) {
        int hr = h0 - 2 + i;
        rows[i][tid + 2] = (hr >= 0 && hr < Hh) ? xp[hr * Ww + tid] : 0.f;
    }
    if (tid < 20) {
        rows[tid][0] = 0.f; rows[tid][1] = 0.f;
        rows[tid][258] = 0.f; rows[tid][259] = 0.f;
    }
    __syncthreads();

    float hw0 = hw[c * 5 + 0], hw1 = hw[c * 5 + 1], hw2 = hw[c * 5 + 2],
          hw3 = hw[c * 5 + 3], hw4 = hw[c * 5 + 4];
    float vw0 = vw[c * 5 + 0], vw1 = vw[c * 5 + 1], vw2 = vw[c * 5 + 2],
          vw3 = vw[c * 5 + 3], vw4 = vw[c * 5 + 4];
    float bias = hb[c] + vb[c];

    ushortT* op = aout + (size_t)bc * PLANE + h0 * Ww + tid;
    #pragma unroll
    for (int r = 0; r < 16; ++r) {
        float hs = hw0 * rows[r + 2][tid]     + hw1 * rows[r + 2][tid + 1]
                 + hw2 * rows[r + 2][tid + 2] + hw3 * rows[r + 2][tid + 3]
                 + hw4 * rows[r + 2][tid + 4];
        float vs = vw0 * rows[r][tid + 2]     + vw1 * rows[r + 1][tid + 2]
                 + vw2 * rows[r + 2][tid + 2] + vw3 * rows[r + 3][tid + 2]
                 + vw4 * rows[r + 4][tid + 2];
        float res = hs + vs + bias + rows[r + 2][tid + 2];
        op[r * Ww] = f2bf(fmaxf(res, 0.f));
    }
}

// ---------- Kernel 1b: pointwise 64x64 via MFMA + fused stats partials ----------
// grid: Bn*256 blocks (256-pixel tiles), 256 threads
__global__ __launch_bounds__(256) void pw_mfma_kernel(
    const ushortT* __restrict__ a_bf, const ushortT* __restrict__ pw_bf,
    const float* __restrict__ pwb,
    float* __restrict__ y_raw, float* __restrict__ sums, float* __restrict__ sumsq)
{
    int blk = blockIdx.x;
    int b = blk >> 8;
    int t0 = (blk & 255) << 8;
    int tid = threadIdx.x, lane = tid & 63, wv = tid >> 6;
    int half = lane >> 4;      // quad 0..3
    int col = lane & 15;

    __shared__ ushortT ytile[256 * 74];   // [pixel][c], stride 74 ushorts (37 words)

    // stage: thread = pixel, transpose into LDS
    {
        size_t base = (size_t)b * Cc * PLANE + t0 + tid;
        uint* wrow = (uint*)&ytile[tid * 74];
        #pragma unroll
        for (int c = 0; c < Cc; c += 2) {
            ushortT v0 = a_bf[base + (size_t)c * PLANE];
            ushortT v1 = a_bf[base + (size_t)(c + 1) * PLANE];
            wrow[c >> 1] = (uint)v0 | ((uint)v1 << 16);
        }
    }
    __syncthreads();

    int m0 = wv * 16;
    BF8U a0, a1;
    a0.u = *(const us8*)(pw_bf + (m0 + col) * 64 + half * 8);
    a1.u = *(const us8*)(pw_bf + (m0 + col) * 64 + 32 + half * 8);

    float bias[4], s[4], s2[4];
    #pragma unroll
    for (int r = 0; r < 4; ++r) {
        bias[r] = pwb[m0 + half * 4 + r];
        s[r] = 0.f; s2[r] = 0.f;
    }

    const uint* lw = (const uint*)ytile;
    #pragma unroll 4
    for (int t = 0; t < 16; ++t) {
        int rbase = (t * 16 + col) * 37 + half * 4;
        BF8U b0, b1;
        b0.w.x = lw[rbase];      b0.w.y = lw[rbase + 1];
        b0.w.z = lw[rbase + 2];  b0.w.w = lw[rbase + 3];
        b1.w.x = lw[rbase + 16]; b1.w.y = lw[rbase + 17];
        b1.w.z = lw[rbase + 18]; b1.w.w = lw[rbase + 19];
        f32x4 acc = (f32x4){0.f, 0.f, 0.f, 0.f};
        acc = __builtin_amdgcn_mfma_f32_16x16x32_bf16(a0.b, b0.b, acc, 0, 0, 0);
        acc = __builtin_amdgcn_mfma_f32_16x16x32_bf16(a1.b, b1.b, acc, 0, 0, 0);
        int pix = t * 16 + col;
        #pragma unroll
        for (int r = 0; r < 4; ++r) {
            int c = m0 + half * 4 + r;
            float v = acc[r] + bias[r];
            y_raw[(size_t)(b * Cc + c) * PLANE + t0 + pix] = v;
            s[r] += v; s2[r] += v * v;
        }
    }
    // reduce over the 16 cols sharing (half, r), then atomic
    #pragma unroll
    for (int r = 0; r < 4; ++r) {
        #pragma unroll
        for (int d = 8; d > 0; d >>= 1) {
            s[r]  += __shfl_down(s[r], d, 16);
            s2[r] += __shfl_down(s2[r], d, 16);
        }
    }
    if (col == 0) {
        #pragma unroll
        for (int r = 0; r < 4; ++r) {
            int c = m0 + half * 4 + r;
            atomicAdd(&sums[b * Cc + c], s[r]);
            atomicAdd(&sumsq[b * Cc + c], s2[r]);
        }
    }
}

// ---------- Kernel 3: fold hybrid norm into per-(b,c) affine ----------
__global__ void finalize_kernel(
    const float* __restrict__ sums, const float* __restrict__ sumsq,
    const float* __restrict__ bn_w, const float* __restrict__ bn_b,
    float* __restrict__ alpha, float* __restrict__ beta)
{
    int c = threadIdx.x;
    if (c >= Cc) return;
    float im[4], e2[4];
    float bm = 0.f, be2 = 0.f;
    for (int b = 0; b < 4; ++b) {
        im[b] = sums[b * Cc + c] * (1.f / 65536.f);
        e2[b] = sumsq[b * Cc + c] * (1.f / 65536.f);
        bm += im[b]; be2 += e2[b];
    }
    bm *= 0.25f; be2 *= 0.25f;
    float bv = be2 - bm * bm;
    float rsb = rsqrtf(bv + 1e-5f);
    float wgt = bn_w[c], bb = bn_b[c];
    for (int b = 0; b < 4; ++b) {
        float iv = e2[b] - im[b] * im[b];
        float rsi = rsqrtf(iv + 1e-5f);
        float al = 0.7f * rsi + 0.3f * rsb * wgt;
        float bt = -0.7f * im[b] * rsi - 0.3f * bm * rsb * wgt + 0.3f * bb;
        alpha[b * Cc + c] = al;
        beta[b * Cc + c] = bt;
    }
}

// ---------- Kernel 4: normalize + q/k/val projections via MFMA ----------
__global__ __launch_bounds__(256) void qkv_mfma_kernel(
    const float* __restrict__ y_raw,
    const float* __restrict__ alpha, const float* __restrict__ beta,
    const ushortT* __restrict__ qk_bf, const float* __restrict__ qbias,
    const float* __restrict__ kbias,
    const ushortT* __restrict__ vw_bf, const float* __restrict__ vbias,
    float* __restrict__ y_norm, float* __restrict__ q, float* __restrict__ k,
    ushortT* __restrict__ val)
{
    int blk = blockIdx.x;
    int b = blk >> 8;
    int t0 = (blk & 255) << 8;
    int tid = threadIdx.x, lane = tid & 63, wv = tid >> 6;
    int half = lane >> 4;
    int col = lane & 15;

    __shared__ ushortT ytile[256 * 74];

    // stage: normalize + write y_norm + transpose bf16 into LDS
    {
        size_t base = (size_t)b * Cc * PLANE + t0 + tid;
        uint* wrow = (uint*)&ytile[tid * 74];
        #pragma unroll
        for (int c = 0; c < Cc; c += 2) {
            float v0 = y_raw[base + (size_t)c * PLANE];
            float v1 = y_raw[base + (size_t)(c + 1) * PLANE];
            float n0 = alpha[b * Cc + c] * v0 + beta[b * Cc + c];
            float n1 = alpha[b * Cc + c + 1] * v1 + beta[b * Cc + c + 1];
            y_norm[base + (size_t)c * PLANE] = n0;
            y_norm[base + (size_t)(c + 1) * PLANE] = n1;
            wrow[c >> 1] = (uint)f2bf(n0) | ((uint)f2bf(n1) << 16);
        }
    }
    __syncthreads();

    const uint* lw = (const uint*)ytile;

    // q/k: M-tile = 16 rows (8 q + 8 k); wave wv handles n-tiles wv*4..wv*4+3
    {
        BF8U a0, a1;
        a0.u = *(const us8*)(qk_bf + col * 64 + half * 8);
        a1.u = *(const us8*)(qk_bf + col * 64 + 32 + half * 8);
        #pragma unroll
        for (int i = 0; i < 4; ++i) {
            int t = wv * 4 + i;
            int rbase = (t * 16 + col) * 37 + half * 4;
            BF8U b0, b1;
            b0.w.x = lw[rbase];      b0.w.y = lw[rbase + 1];
            b0.w.z = lw[rbase + 2];  b0.w.w = lw[rbase + 3];
            b1.w.x = lw[rbase + 16]; b1.w.y = lw[rbase + 17];
            b1.w.z = lw[rbase + 18]; b1.w.w = lw[rbase + 19];
            f32x4 acc = (f32x4){0.f, 0.f, 0.f, 0.f};
            acc = __builtin_amdgcn_mfma_f32_16x16x32_bf16(a0.b, b0.b, acc, 0, 0, 0);
            acc = __builtin_amdgcn_mfma_f32_16x16x32_bf16(a1.b, b1.b, acc, 0, 0, 0);
            int pix = t * 16 + col;
            #pragma unroll
            for (int r = 0; r < 4; ++r) {
                int row = half * 4 + r;
                if (row < 8)
                    q[(size_t)(b * CQn + row) * PLANE + t0 + pix] = acc[r] + qbias[row];
                else
                    k[(size_t)(b * CQn + row - 8) * PLANE + t0 + pix] = acc[r] + kbias[row - 8];
            }
        }
    }

    // val: wave wv owns c-tile m0=wv*16, sweeps 16 n-tiles
    {
        int m0 = wv * 16;
        BF8U a0, a1;
        a0.u = *(const us8*)(vw_bf + (m0 + col) * 64 + half * 8);
        a1.u = *(const us8*)(vw_bf + (m0 + col) * 64 + 32 + half * 8);
        float bias[4];
        #pragma unroll
        for (int r = 0; r < 4; ++r) bias[r] = vbias[m0 + half * 4 + r];
        #pragma unroll 4
        for (int t = 0; t < 16; ++t) {
            int rbase = (t * 16 + col) * 37 + half * 4;
            BF8U b0, b1;
            b0.w.x = lw[rbase];      b0.w.y = lw[rbase + 1];
            b0.w.z = lw[rbase + 2];  b0.w.w = lw[rbase + 3];
            b1.w.x = lw[rbase + 16]; b1.w.y = lw[rbase + 17];
            b1.w.z = lw[rbase + 18]; b1.w.w = lw[rbase + 19];
            f32x4 acc = (f32x4){0.f, 0.f, 0.f, 0.f};
            acc = __builtin_amdgcn_mfma_f32_16x16x32_bf16(a0.b, b0.b, acc, 0, 0, 0);
            acc = __builtin_amdgcn_mfma_f32_16x16x32_bf16(a1.b, b1.b, acc, 0, 0, 0);
            int pix = t * 16 + col;
            #pragma unroll
            for (int r = 0; r < 4; ++r) {
                int c = m0 + half * 4 + r;
                val[(size_t)(b * Cc + c) * PLANE + t0 + pix] = f2bf(acc[r] + bias[r]);
            }
        }
    }
}

// ---------- Kernel 5a: batched 256x256 fp32 plane transpose ----------
__global__ __launch_bounds__(256) void transpose_kernel(
    const float* __restrict__ src, float* __restrict__ dst)
{
    int blk = blockIdx.x;
    int plane = blk >> 6;
    int tile = blk & 63;
    int th = (tile >> 3) * 32;
    int tw = (tile & 7) * 32;
    __shared__ float t[32][33];
    const float* s = src + (size_t)plane * PLANE;
    float* d = dst + (size_t)plane * PLANE;
    int lw = threadIdx.x & 31;
    int lh = threadIdx.x >> 5;
    #pragma unroll
    for (int i = 0; i < 4; ++i)
        t[lh + 8 * i][lw] = s[(th + lh + 8 * i) * Ww + tw + lw];
    __syncthreads();
    #pragma unroll
    for (int i = 0; i < 4; ++i)
        d[(tw + lh + 8 * i) * Hh + th + lw] = t[lw][lh + 8 * i];
}

// ---------- Kernel 5b: batched 256x256 bf16 plane transpose ----------
__global__ __launch_bounds__(256) void transpose16_kernel(
    const ushortT* __restrict__ src, ushortT* __restrict__ dst)
{
    int blk = blockIdx.x;
    int plane = blk >> 6;
    int tile = blk & 63;
    int th = (tile >> 3) * 32;
    int tw = (tile & 7) * 32;
    __shared__ ushortT t[32][34];
    const ushortT* s = src + (size_t)plane * PLANE;
    ushortT* d = dst + (size_t)plane * PLANE;
    int lw = threadIdx.x & 31;
    int lh = threadIdx.x >> 5;
    #pragma unroll
    for (int i = 0; i < 4; ++i)
        t[lh + 8 * i][lw] = s[(th + lh + 8 * i) * Ww + tw + lw];
    __syncthreads();
    #pragma unroll
    for (int i = 0; i < 4; ++i)
        d[(tw + lh + 8 * i) * Hh + th + lw] = t[lw][lh + 8 * i];
}

// ---------- Kernel 6: MFMA row attention ----------
template<bool BF16OUT>
__global__ __launch_bounds__(256) void attn_mfma_kernel(
    const float* __restrict__ q, const float* __restrict__ k,
    const ushortT* __restrict__ val, void* __restrict__ outp)
{
    int blk = blockIdx.x;
    int b = blk >> 8;
    int r = blk & 255;
    int tid = threadIdx.x;
    int lane = tid & 63;
    int wv = tid >> 6;

    __shared__ ushortT val_lds[64 * 264];
    __shared__ ushortT A_lds[256 * 40];
    __shared__ float qsh[256 * 8];
    __shared__ float ksh[256 * 8];
    __shared__ float mlb[256 * 2];

    size_t qbase = (size_t)b * CQn * PLANE + (size_t)r * Ww;
    float qreg[8], kreg[8];
    #pragma unroll
    for (int c = 0; c < 8; ++c) {
        float qv = q[qbase + (size_t)c * PLANE + tid];
        float kv = k[qbase + (size_t)c * PLANE + tid];
        qsh[tid * 8 + c] = qv; ksh[tid * 8 + c] = kv;
        qreg[c] = qv; kreg[c] = kv;
    }
    size_t vbase = (size_t)b * Cc * PLANE + (size_t)r * Ww;
    {
        int crow = tid >> 5;
        int chunk = tid & 31;
        #pragma unroll
        for (int pass = 0; pass < 8; ++pass) {
            int c = pass * 8 + crow;
            us8 v = *(const us8*)(val + vbase + (size_t)c * PLANE + chunk * 8);
            *(us8*)&val_lds[c * 264 + chunk * 8] = v;
        }
    }
    __syncthreads();

    float m = -1e30f, l = 0.f;
    for (int i = 0; i < 256; ++i) {
        const float* kr = &ksh[i * 8];
        float s = qreg[0] * kr[0] + qreg[1] * kr[1] + qreg[2] * kr[2] + qreg[3] * kr[3]
                + qreg[4] * kr[4] + qreg[5] * kr[5] + qreg[6] * kr[6] + qreg[7] * kr[7];
        float nm = fmaxf(m, s);
        l = l * __expf(m - nm) + __expf(s - nm);
        m = nm;
    }
    mlb[tid * 2 + 0] = m;
    mlb[tid * 2 + 1] = 1.f / l;
    __syncthreads();

    f32x4 acc[16];
    #pragma unroll
    for (int t = 0; t < 16; ++t) acc[t] = (f32x4){0.f, 0.f, 0.f, 0.f};

    for (int ks = 0; ks < 8; ++ks) {
        int j0 = ks * 32;
        #pragma unroll
        for (int chunk = 0; chunk < 4; ++chunk) {
            bf16x8 pk;
            #pragma unroll
            for (int jj = 0; jj < 8; ++jj) {
                int j = j0 + chunk * 8 + jj;
                const float* qr = &qsh[j * 8];
                float s = qr[0] * kreg[0] + qr[1] * kreg[1] + qr[2] * kreg[2] + qr[3] * kreg[3]
                        + qr[4] * kreg[4] + qr[5] * kreg[5] + qr[6] * kreg[6] + qr[7] * kreg[7];
                float aw = __expf(s - mlb[j * 2 + 0]) * mlb[j * 2 + 1];
                pk[jj] = (__bf16)aw;
            }
            *(bf16x8*)&A_lds[tid * 40 + chunk * 8] = pk;
        }
        __syncthreads();
        bf16x8 af = *(const bf16x8*)&val_lds[(wv * 16 + (lane & 15)) * 264 + j0 + (lane >> 4) * 8];
        #pragma unroll
        for (int t = 0; t < 16; ++t) {
            bf16x8 bf = *(const bf16x8*)&A_lds[(t * 16 + (lane & 15)) * 40 + (lane >> 4) * 8];
            acc[t] = __builtin_amdgcn_mfma_f32_16x16x32_bf16(af, bf, acc[t], 0, 0, 0);
        }
        __syncthreads();
    }

    size_t obase = (size_t)b * Cc * PLANE + (size_t)r * Ww;
    #pragma unroll
    for (int t = 0; t < 16; ++t) {
        int i = t * 16 + (lane & 15);
        #pragma unroll
        for (int rr = 0; rr < 4; ++rr) {
            int c = wv * 16 + (lane >> 4) * 4 + rr;
            float v = acc[t][rr];
            size_t addr = obase + (size_t)c * PLANE + i;
            if (BF16OUT) ((__hip_bfloat16*)outp)[addr] = __float2bfloat16(v);
            else         ((float*)outp)[addr] = v;
        }
    }
}

// ---------- Kernel 7: combine + residual + 2x2 maxpool ----------
__global__ __launch_bounds__(256) void final_kernel(
    const ushortT* __restrict__ houtT, const float* __restrict__ y_norm,
    const float* __restrict__ gamma,
    float* __restrict__ out, float* __restrict__ down)
{
    int blk = blockIdx.x;
    int tile = blk & 63;
    int bc = blk >> 6;
    int th = (tile >> 3) * 32;
    int tw = (tile & 7) * 32;
    __shared__ float t[32][33];
    const ushortT* hT = houtT + (size_t)bc * PLANE;
    {
        int ww = threadIdx.x >> 3;
        int hh = (threadIdx.x & 7) * 4;
        us4 v4 = *(const us4*)(hT + (size_t)(tw + ww) * Hh + th + hh);
        t[hh + 0][ww] = __uint_as_float((unsigned)v4[0] << 16);
        t[hh + 1][ww] = __uint_as_float((unsigned)v4[1] << 16);
        t[hh + 2][ww] = __uint_as_float((unsigned)v4[2] << 16);
        t[hh + 3][ww] = __uint_as_float((unsigned)v4[3] << 16);
    }
    __syncthreads();
    float g = gamma[0];
    int qw_ = threadIdx.x & 15;
    int qh_ = threadIdx.x >> 4;
    const float* yb = y_norm + (size_t)bc * PLANE;
    float* ob = out + (size_t)bc * PLANE;
    float mx = -1e30f;
    float2 res[2];
    #pragma unroll
    for (int i = 0; i < 2; ++i) {
        int hh = 2 * qh_ + i;
        int off = (th + hh) * Ww + tw + 2 * qw_;
        float2 v = *(const float2*)(ob + off);
        float2 y = *(const float2*)(yb + off);
        float o0 = g * (t[hh][2 * qw_]     + v.x) + y.x;
        float o1 = g * (t[hh][2 * qw_ + 1] + v.y) + y.y;
        res[i] = make_float2(o0, o1);
        mx = fmaxf(mx, fmaxf(o0, o1));
    }
    #pragma unroll
    for (int i = 0; i < 2; ++i) {
        int off = (th + 2 * qh_ + i) * Ww + tw + 2 * qw_;
        *(float2*)(ob + off) = res[i];
    }
    down[(size_t)bc * 16384 + (th / 2 + qh_) * 128 + tw / 2 + qw_] = mx;
}

extern "C" void kernel_launch(void* const* d_in, const int* in_sizes, int n_in,
                              void* d_out, int out_size, void* d_ws, size_t ws_size,
                              hipStream_t stream)
{
    const float* x     = (const float*)d_in[0];
    const float* hw    = (const float*)d_in[1];
    const float* hb    = (const float*)d_in[2];
    const float* vw    = (const float*)d_in[3];
    const float* vb    = (const float*)d_in[4];
    const float* pww   = (const float*)d_in[5];
    const float* pwb   = (const float*)d_in[6];
    const float* bnw   = (const float*)d_in[7];
    const float* bnb   = (const float*)d_in[8];
    const float* qw    = (const float*)d_in[9];
    const float* qb    = (const float*)d_in[10];
    const float* kw    = (const float*)d_in[11];
    const float* kb    = (const float*)d_in[12];
    const float* vw2   = (const float*)d_in[13];
    const float* vb2   = (const float*)d_in[14];
    const float* gamma = (const float*)d_in[15];

    float* ws = (float*)d_ws;
    const size_t NP = (size_t)Bn * Cc * PLANE;   // 16.7M
    const size_t NQ = (size_t)Bn * CQn * PLANE;  // 2.1M
    float* y_raw  = ws;                      // [NP]
    float* y_norm = ws + NP;                 // [NP]
    float* slotC  = ws + 2 * NP;             // a_buf bf16 -> valT bf16 [NP/2 floats]
    float* slotD  = ws + 2 * NP + NP / 2;    // val bf16 -> houtT bf16 [NP/2 floats]
    float* qbuf   = ws + 3 * NP;
    float* kbuf   = qbuf + NQ;
    float* qT     = kbuf + NQ;
    float* kT     = qT + NQ;
    float* sums   = kT + NQ;                 // 256
    float* sumsq  = sums + 256;              // 256
    float* alpha  = sumsq + 256;             // 256
    float* beta   = alpha + 256;             // 256
    ushortT* pw_bf = (ushortT*)(beta + 256);       // 4096 us
    ushortT* qk_bf = pw_bf + 64 * 64;              // 1024 us
    ushortT* vw_bf = qk_bf + 16 * 64;              // 4096 us

    ushortT* a_buf = (ushortT*)slotC;
    ushortT* valT  = (ushortT*)slotC;   // a dead after pw
    ushortT* valb  = (ushortT*)slotD;
    ushortT* houtT = (ushortT*)slotD;   // val dead after width attn
    float* out  = (float*)d_out;
    float* down = out + NP;

    hipMemsetAsync(sums, 0, 512 * sizeof(float), stream);
    pack_weights_kernel<<<dim3(16), dim3(256), 0, stream>>>(
        pww, qw, kw, vw2, pw_bf, qk_bf, vw_bf);
    dw_kernel<<<dim3(Bn * Cc * 16), dim3(256), 0, stream>>>(
        x, hw, hb, vw, vb, a_buf);
    pw_mfma_kernel<<<dim3(Bn * 256), dim3(256), 0, stream>>>(
        a_buf, pw_bf, pwb, y_raw, sums, sumsq);
    finalize_kernel<<<dim3(1), dim3(64), 0, stream>>>(
        sums, sumsq, bnw, bnb, alpha, beta);
    qkv_mfma_kernel<<<dim3(Bn * 256), dim3(256), 0, stream>>>(
        y_raw, alpha, beta, qk_bf, qb, kb, vw_bf, vb2,
        y_norm, qbuf, kbuf, valb);
    transpose_kernel<<<dim3(Bn * CQn * 64), dim3(256), 0, stream>>>(qbuf, qT);
    transpose_kernel<<<dim3(Bn * CQn * 64), dim3(256), 0, stream>>>(kbuf, kT);
    transpose16_kernel<<<dim3(Bn * Cc * 64), dim3(256), 0, stream>>>(valb, valT);
    attn_mfma_kernel<false><<<dim3(Bn * Hh), dim3(256), 0, stream>>>(
        qbuf, kbuf, valb, (void*)out);
    attn_mfma_kernel<true><<<dim3(Bn * Hh), dim3(256), 0, stream>>>(
        qT, kT, valT, (void*)houtT);
    final_kernel<<<dim3(Bn * Cc * 64), dim3(256), 0, stream>>>(
        houtT, y_norm, gamma, out, down);
}

// Round 5
// 424.919 us; speedup vs baseline: 3.1991x; 1.2347x over previous
//
#include <hip/hip_runtime.h>
#include <hip/hip_bf16.h>

#define Bn 4
#define Cc 64
#define CQn 8
#define Hh 256
#define Ww 256
#define PLANE 65536

typedef unsigned short ushortT;
typedef __attribute__((ext_vector_type(8))) unsigned short us8;
typedef __attribute__((ext_vector_type(4))) unsigned short us4;
typedef __attribute__((ext_vector_type(8))) __bf16 bf16x8;
typedef __attribute__((ext_vector_type(4))) float f32x4;

__device__ inline ushortT f2bf(float f) {
    __hip_bfloat16 h = __float2bfloat16(f);
    return *(ushortT*)&h;
}
__device__ inline float bf2f(ushortT u) {
    return __uint_as_float((unsigned)u << 16);
}
union BF8U { us8 u; bf16x8 b; uint4 w; };
__device__ inline us8 zero_us8() {
    BF8U z; z.w.x = 0; z.w.y = 0; z.w.z = 0; z.w.w = 0; return z.u;
}

// ---------- Kernel 0: pack weights to bf16 ----------
__global__ void pack_weights_kernel(
    const float* __restrict__ pww, const float* __restrict__ qw,
    const float* __restrict__ kw, const float* __restrict__ vw,
    ushortT* __restrict__ pw_bf, ushortT* __restrict__ qk_bf,
    ushortT* __restrict__ vw_bf)
{
    int i = blockIdx.x * 256 + threadIdx.x;
    if (i < 64 * 64) pw_bf[i] = f2bf(pww[i]);
    if (i < 64 * 64) vw_bf[i] = f2bf(vw[i]);
    if (i < 8 * 64)  qk_bf[i] = f2bf(qw[i]);
    if (i >= 8 * 64 && i < 16 * 64) qk_bf[i] = f2bf(kw[i - 512]);
}

// ---------- Kernel 1a: axial depthwise conv + relu (bf16 out) ----------
__global__ __launch_bounds__(256) void dw_kernel(
    const float* __restrict__ x,
    const float* __restrict__ hw, const float* __restrict__ hb,
    const float* __restrict__ vw, const float* __restrict__ vb,
    ushortT* __restrict__ aout)
{
    int blk = blockIdx.x;
    int bc = blk >> 4;
    int ht = blk & 15;
    int h0 = ht * 16;
    int c = bc & 63;
    int tid = threadIdx.x;
    __shared__ float rows[20][260];
    const float* xp = x + (size_t)bc * PLANE;
    #pragma unroll
    for (int i = 0; i < 20; ++i) {
        int hr = h0 - 2 + i;
        rows[i][tid + 2] = (hr >= 0 && hr < Hh) ? xp[hr * Ww + tid] : 0.f;
    }
    if (tid < 20) {
        rows[tid][0] = 0.f; rows[tid][1] = 0.f;
        rows[tid][258] = 0.f; rows[tid][259] = 0.f;
    }
    __syncthreads();

    float hw0 = hw[c * 5 + 0], hw1 = hw[c * 5 + 1], hw2 = hw[c * 5 + 2],
          hw3 = hw[c * 5 + 3], hw4 = hw[c * 5 + 4];
    float vw0 = vw[c * 5 + 0], vw1 = vw[c * 5 + 1], vw2 = vw[c * 5 + 2],
          vw3 = vw[c * 5 + 3], vw4 = vw[c * 5 + 4];
    float bias = hb[c] + vb[c];

    ushortT* op = aout + (size_t)bc * PLANE + h0 * Ww + tid;
    #pragma unroll
    for (int r = 0; r < 16; ++r) {
        float hs = hw0 * rows[r + 2][tid]     + hw1 * rows[r + 2][tid + 1]
                 + hw2 * rows[r + 2][tid + 2] + hw3 * rows[r + 2][tid + 3]
                 + hw4 * rows[r + 2][tid + 4];
        float vs = vw0 * rows[r][tid + 2]     + vw1 * rows[r + 1][tid + 2]
                 + vw2 * rows[r + 2][tid + 2] + vw3 * rows[r + 3][tid + 2]
                 + vw4 * rows[r + 4][tid + 2];
        float res = hs + vs + bias + rows[r + 2][tid + 2];
        op[r * Ww] = f2bf(fmaxf(res, 0.f));
    }
}

// ---------- Kernel 1b: pointwise 64x64 via MFMA + fused stats partials ----------
__global__ __launch_bounds__(256) void pw_mfma_kernel(
    const ushortT* __restrict__ a_bf, const ushortT* __restrict__ pw_bf,
    const float* __restrict__ pwb,
    float* __restrict__ y_raw, float* __restrict__ sums, float* __restrict__ sumsq)
{
    int blk = blockIdx.x;
    int b = blk >> 8;
    int t0 = (blk & 255) << 8;
    int tid = threadIdx.x, lane = tid & 63, wv = tid >> 6;
    int half = lane >> 4;
    int col = lane & 15;

    __shared__ ushortT ytile[256 * 74];

    {
        size_t base = (size_t)b * Cc * PLANE + t0 + tid;
        uint* wrow = (uint*)&ytile[tid * 74];
        #pragma unroll
        for (int c = 0; c < Cc; c += 2) {
            ushortT v0 = a_bf[base + (size_t)c * PLANE];
            ushortT v1 = a_bf[base + (size_t)(c + 1) * PLANE];
            wrow[c >> 1] = (uint)v0 | ((uint)v1 << 16);
        }
    }
    __syncthreads();

    int m0 = wv * 16;
    BF8U a0, a1;
    a0.u = *(const us8*)(pw_bf + (m0 + col) * 64 + half * 8);
    a1.u = *(const us8*)(pw_bf + (m0 + col) * 64 + 32 + half * 8);

    float bias[4], s[4], s2[4];
    #pragma unroll
    for (int r = 0; r < 4; ++r) {
        bias[r] = pwb[m0 + half * 4 + r];
        s[r] = 0.f; s2[r] = 0.f;
    }

    const uint* lw = (const uint*)ytile;
    #pragma unroll 4
    for (int t = 0; t < 16; ++t) {
        int rbase = (t * 16 + col) * 37 + half * 4;
        BF8U b0, b1;
        b0.w.x = lw[rbase];      b0.w.y = lw[rbase + 1];
        b0.w.z = lw[rbase + 2];  b0.w.w = lw[rbase + 3];
        b1.w.x = lw[rbase + 16]; b1.w.y = lw[rbase + 17];
        b1.w.z = lw[rbase + 18]; b1.w.w = lw[rbase + 19];
        f32x4 acc = (f32x4){0.f, 0.f, 0.f, 0.f};
        acc = __builtin_amdgcn_mfma_f32_16x16x32_bf16(a0.b, b0.b, acc, 0, 0, 0);
        acc = __builtin_amdgcn_mfma_f32_16x16x32_bf16(a1.b, b1.b, acc, 0, 0, 0);
        int pix = t * 16 + col;
        #pragma unroll
        for (int r = 0; r < 4; ++r) {
            int c = m0 + half * 4 + r;
            float v = acc[r] + bias[r];
            y_raw[(size_t)(b * Cc + c) * PLANE + t0 + pix] = v;
            s[r] += v; s2[r] += v * v;
        }
    }
    #pragma unroll
    for (int r = 0; r < 4; ++r) {
        #pragma unroll
        for (int d = 8; d > 0; d >>= 1) {
            s[r]  += __shfl_down(s[r], d, 16);
            s2[r] += __shfl_down(s2[r], d, 16);
        }
    }
    if (col == 0) {
        #pragma unroll
        for (int r = 0; r < 4; ++r) {
            int c = m0 + half * 4 + r;
            atomicAdd(&sums[b * Cc + c], s[r]);
            atomicAdd(&sumsq[b * Cc + c], s2[r]);
        }
    }
}

// ---------- Kernel 3: fold hybrid norm into per-(b,c) affine ----------
__global__ void finalize_kernel(
    const float* __restrict__ sums, const float* __restrict__ sumsq,
    const float* __restrict__ bn_w, const float* __restrict__ bn_b,
    float* __restrict__ alpha, float* __restrict__ beta)
{
    int c = threadIdx.x;
    if (c >= Cc) return;
    float im[4], e2[4];
    float bm = 0.f, be2 = 0.f;
    for (int b = 0; b < 4; ++b) {
        im[b] = sums[b * Cc + c] * (1.f / 65536.f);
        e2[b] = sumsq[b * Cc + c] * (1.f / 65536.f);
        bm += im[b]; be2 += e2[b];
    }
    bm *= 0.25f; be2 *= 0.25f;
    float bv = be2 - bm * bm;
    float rsb = rsqrtf(bv + 1e-5f);
    float wgt = bn_w[c], bb = bn_b[c];
    for (int b = 0; b < 4; ++b) {
        float iv = e2[b] - im[b] * im[b];
        float rsi = rsqrtf(iv + 1e-5f);
        float al = 0.7f * rsi + 0.3f * rsb * wgt;
        float bt = -0.7f * im[b] * rsi - 0.3f * bm * rsb * wgt + 0.3f * bb;
        alpha[b * Cc + c] = al;
        beta[b * Cc + c] = bt;
    }
}

// ---------- Kernel 4: normalize + q/k/val projections via MFMA (q,k,val bf16) ----------
__global__ __launch_bounds__(256) void qkv_mfma_kernel(
    const float* __restrict__ y_raw,
    const float* __restrict__ alpha, const float* __restrict__ beta,
    const ushortT* __restrict__ qk_bf, const float* __restrict__ qbias,
    const float* __restrict__ kbias,
    const ushortT* __restrict__ vw_bf, const float* __restrict__ vbias,
    float* __restrict__ y_norm, ushortT* __restrict__ q, ushortT* __restrict__ k,
    ushortT* __restrict__ val)
{
    int blk = blockIdx.x;
    int b = blk >> 8;
    int t0 = (blk & 255) << 8;
    int tid = threadIdx.x, lane = tid & 63, wv = tid >> 6;
    int half = lane >> 4;
    int col = lane & 15;

    __shared__ ushortT ytile[256 * 74];

    {
        size_t base = (size_t)b * Cc * PLANE + t0 + tid;
        uint* wrow = (uint*)&ytile[tid * 74];
        #pragma unroll
        for (int c = 0; c < Cc; c += 2) {
            float v0 = y_raw[base + (size_t)c * PLANE];
            float v1 = y_raw[base + (size_t)(c + 1) * PLANE];
            float n0 = alpha[b * Cc + c] * v0 + beta[b * Cc + c];
            float n1 = alpha[b * Cc + c + 1] * v1 + beta[b * Cc + c + 1];
            y_norm[base + (size_t)c * PLANE] = n0;
            y_norm[base + (size_t)(c + 1) * PLANE] = n1;
            wrow[c >> 1] = (uint)f2bf(n0) | ((uint)f2bf(n1) << 16);
        }
    }
    __syncthreads();

    const uint* lw = (const uint*)ytile;

    {
        BF8U a0, a1;
        a0.u = *(const us8*)(qk_bf + col * 64 + half * 8);
        a1.u = *(const us8*)(qk_bf + col * 64 + 32 + half * 8);
        #pragma unroll
        for (int i = 0; i < 4; ++i) {
            int t = wv * 4 + i;
            int rbase = (t * 16 + col) * 37 + half * 4;
            BF8U b0, b1;
            b0.w.x = lw[rbase];      b0.w.y = lw[rbase + 1];
            b0.w.z = lw[rbase + 2];  b0.w.w = lw[rbase + 3];
            b1.w.x = lw[rbase + 16]; b1.w.y = lw[rbase + 17];
            b1.w.z = lw[rbase + 18]; b1.w.w = lw[rbase + 19];
            f32x4 acc = (f32x4){0.f, 0.f, 0.f, 0.f};
            acc = __builtin_amdgcn_mfma_f32_16x16x32_bf16(a0.b, b0.b, acc, 0, 0, 0);
            acc = __builtin_amdgcn_mfma_f32_16x16x32_bf16(a1.b, b1.b, acc, 0, 0, 0);
            int pix = t * 16 + col;
            #pragma unroll
            for (int r = 0; r < 4; ++r) {
                int row = half * 4 + r;
                if (row < 8)
                    q[(size_t)(b * CQn + row) * PLANE + t0 + pix] = f2bf(acc[r] + qbias[row]);
                else
                    k[(size_t)(b * CQn + row - 8) * PLANE + t0 + pix] = f2bf(acc[r] + kbias[row - 8]);
            }
        }
    }

    {
        int m0 = wv * 16;
        BF8U a0, a1;
        a0.u = *(const us8*)(vw_bf + (m0 + col) * 64 + half * 8);
        a1.u = *(const us8*)(vw_bf + (m0 + col) * 64 + 32 + half * 8);
        float bias[4];
        #pragma unroll
        for (int r = 0; r < 4; ++r) bias[r] = vbias[m0 + half * 4 + r];
        #pragma unroll 4
        for (int t = 0; t < 16; ++t) {
            int rbase = (t * 16 + col) * 37 + half * 4;
            BF8U b0, b1;
            b0.w.x = lw[rbase];      b0.w.y = lw[rbase + 1];
            b0.w.z = lw[rbase + 2];  b0.w.w = lw[rbase + 3];
            b1.w.x = lw[rbase + 16]; b1.w.y = lw[rbase + 17];
            b1.w.z = lw[rbase + 18]; b1.w.w = lw[rbase + 19];
            f32x4 acc = (f32x4){0.f, 0.f, 0.f, 0.f};
            acc = __builtin_amdgcn_mfma_f32_16x16x32_bf16(a0.b, b0.b, acc, 0, 0, 0);
            acc = __builtin_amdgcn_mfma_f32_16x16x32_bf16(a1.b, b1.b, acc, 0, 0, 0);
            int pix = t * 16 + col;
            #pragma unroll
            for (int r = 0; r < 4; ++r) {
                int c = m0 + half * 4 + r;
                val[(size_t)(b * Cc + c) * PLANE + t0 + pix] = f2bf(acc[r] + bias[r]);
            }
        }
    }
}

// ---------- Kernel 5: batched 256x256 bf16 plane transpose ----------
__global__ __launch_bounds__(256) void transpose16_kernel(
    const ushortT* __restrict__ src, ushortT* __restrict__ dst)
{
    int blk = blockIdx.x;
    int plane = blk >> 6;
    int tile = blk & 63;
    int th = (tile >> 3) * 32;
    int tw = (tile & 7) * 32;
    __shared__ ushortT t[32][34];
    const ushortT* s = src + (size_t)plane * PLANE;
    ushortT* d = dst + (size_t)plane * PLANE;
    int lw = threadIdx.x & 31;
    int lh = threadIdx.x >> 5;
    #pragma unroll
    for (int i = 0; i < 4; ++i)
        t[lh + 8 * i][lw] = s[(th + lh + 8 * i) * Ww + tw + lw];
    __syncthreads();
    #pragma unroll
    for (int i = 0; i < 4; ++i)
        d[(tw + lh + 8 * i) * Hh + th + lw] = t[lw][lh + 8 * i];
}

// ---------- Kernel 6: full-MFMA row attention ----------
// S = Q^T K via MFMA (K=8 in quad-0 slots), shift = mhat + ln(sum exp(S-mhat)),
// A = exp(S - shift) (already normalized), AV via MFMA.
template<bool BF16OUT>
__global__ __launch_bounds__(256) void attn_mfma2_kernel(
    const ushortT* __restrict__ q, const ushortT* __restrict__ k,
    const ushortT* __restrict__ val, void* __restrict__ outp)
{
    int blk = blockIdx.x;
    int b = blk >> 8;
    int r = blk & 255;
    int tid = threadIdx.x;
    int lane = tid & 63;
    int wv = tid >> 6;
    int col = lane & 15;
    int quad = lane >> 4;

    __shared__ ushortT q_s[256 * 8];        // [j][c] bf16, 16B rows
    __shared__ ushortT k_s[256 * 8];        // [i][c]
    __shared__ ushortT val_lds[64 * 264];   // [c][j], 16B-aligned rows
    __shared__ ushortT A_lds[256 * 4 * 8];  // chunk (i*4 + jq) of 8 bf16 j's
    __shared__ float mhat[256];
    __shared__ float shiftv[256];
    __shared__ float kred[32];

    // ---- stage q,k (bf16 global, 8 channels strided by PLANE) ----
    size_t qkbase = (size_t)b * CQn * PLANE + (size_t)r * Ww + tid;
    float qf[8], ka[8];
    {
        BF8U qp, kp;
        #pragma unroll
        for (int c = 0; c < 8; ++c) {
            ushortT qv = q[qkbase + (size_t)c * PLANE];
            ushortT kv = k[qkbase + (size_t)c * PLANE];
            qp.u[c] = qv; kp.u[c] = kv;
            qf[c] = bf2f(qv);
            ka[c] = fabsf(bf2f(kv));
        }
        *(us8*)&q_s[tid * 8] = qp.u;
        *(us8*)&k_s[tid * 8] = kp.u;
    }
    // per-wave abs-max of k per channel
    #pragma unroll
    for (int d = 1; d < 64; d <<= 1)
        #pragma unroll
        for (int c = 0; c < 8; ++c)
            ka[c] = fmaxf(ka[c], __shfl_xor(ka[c], d));
    if (lane == 0)
        #pragma unroll
        for (int c = 0; c < 8; ++c) kred[wv * 8 + c] = ka[c];

    // ---- stage val (bf16) ----
    size_t vbase = (size_t)b * Cc * PLANE + (size_t)r * Ww;
    {
        int c = tid >> 2, sub = tid & 3;
        #pragma unroll
        for (int p = 0; p < 8; ++p) {
            int j0 = (p * 4 + sub) * 8;
            us8 v = *(const us8*)(val + vbase + (size_t)c * PLANE + j0);
            *(us8*)&val_lds[c * 264 + j0] = v;
        }
    }
    __syncthreads();

    // mhat[j] = sum_c |q_c| * kmax_c  (safe upper bound on S row max)
    {
        float mh = 0.f;
        #pragma unroll
        for (int c = 0; c < 8; ++c) {
            float km = fmaxf(fmaxf(kred[c], kred[8 + c]),
                             fmaxf(kred[16 + c], kred[24 + c]));
            mh += fabsf(qf[c]) * km;
        }
        mhat[tid] = mh;
    }
    __syncthreads();

    // ---- phase 1: l[j] via MFMA sweep; shift = mhat + ln(l) ----
    #pragma unroll
    for (int t = 0; t < 4; ++t) {
        int jt = wv * 4 + t;
        BF8U qa; qa.u = zero_us8();
        if (quad == 0) qa.u = *(const us8*)&q_s[(jt * 16 + col) * 8];
        float mh4[4];
        #pragma unroll
        for (int rr = 0; rr < 4; ++rr) mh4[rr] = mhat[jt * 16 + quad * 4 + rr];
        f32x4 ls = (f32x4){0.f, 0.f, 0.f, 0.f};
        for (int it = 0; it < 16; ++it) {
            BF8U kb; kb.u = zero_us8();
            if (quad == 0) kb.u = *(const us8*)&k_s[(it * 16 + col) * 8];
            f32x4 sacc = (f32x4){0.f, 0.f, 0.f, 0.f};
            sacc = __builtin_amdgcn_mfma_f32_16x16x32_bf16(qa.b, kb.b, sacc, 0, 0, 0);
            #pragma unroll
            for (int rr = 0; rr < 4; ++rr)
                ls[rr] += __expf(sacc[rr] - mh4[rr]);
        }
        #pragma unroll
        for (int d = 1; d < 16; d <<= 1)
            #pragma unroll
            for (int rr = 0; rr < 4; ++rr)
                ls[rr] += __shfl_xor(ls[rr], d);
        if (col == 0)
            #pragma unroll
            for (int rr = 0; rr < 4; ++rr)
                shiftv[jt * 16 + quad * 4 + rr] = mh4[rr] + __logf(ls[rr]);
    }
    __syncthreads();

    // ---- phase 2: per 32-j slab: produce A = exp(S - shift), consume via AV MFMA ----
    BF8U kc[4];
    #pragma unroll
    for (int i = 0; i < 4; ++i) {
        kc[i].u = zero_us8();
        if (quad == 0) kc[i].u = *(const us8*)&k_s[((wv * 4 + i) * 16 + col) * 8];
    }
    f32x4 acc[16];
    #pragma unroll
    for (int t = 0; t < 16; ++t) acc[t] = (f32x4){0.f, 0.f, 0.f, 0.f};

    for (int ks = 0; ks < 8; ++ks) {
        #pragma unroll
        for (int jj2 = 0; jj2 < 2; ++jj2) {
            int jt = ks * 2 + jj2;
            BF8U qa; qa.u = zero_us8();
            if (quad == 0) qa.u = *(const us8*)&q_s[(jt * 16 + col) * 8];
            float sh4[4];
            #pragma unroll
            for (int rr = 0; rr < 4; ++rr) sh4[rr] = shiftv[jt * 16 + quad * 4 + rr];
            #pragma unroll
            for (int i = 0; i < 4; ++i) {
                f32x4 sacc = (f32x4){0.f, 0.f, 0.f, 0.f};
                sacc = __builtin_amdgcn_mfma_f32_16x16x32_bf16(qa.b, kc[i].b, sacc, 0, 0, 0);
                us4 pk;
                #pragma unroll
                for (int rr = 0; rr < 4; ++rr)
                    pk[rr] = f2bf(__expf(sacc[rr] - sh4[rr]));
                int irow = (wv * 4 + i) * 16 + col;
                int jq = jj2 * 2 + (quad >> 1);
                *(us4*)&A_lds[(irow * 4 + jq) * 8 + (quad & 1) * 4] = pk;
            }
        }
        __syncthreads();
        BF8U af;
        af.u = *(const us8*)&val_lds[(wv * 16 + col) * 264 + ks * 32 + quad * 8];
        #pragma unroll
        for (int t = 0; t < 16; ++t) {
            BF8U bfr;
            bfr.u = *(const us8*)&A_lds[((t * 16 + col) * 4 + quad) * 8];
            acc[t] = __builtin_amdgcn_mfma_f32_16x16x32_bf16(af.b, bfr.b, acc[t], 0, 0, 0);
        }
        __syncthreads();
    }

    // store: C/D layout col=i, row c=quad*4+rr; wave wv owns c-tile wv
    size_t obase = (size_t)b * Cc * PLANE + (size_t)r * Ww;
    #pragma unroll
    for (int t = 0; t < 16; ++t) {
        int i = t * 16 + col;
        #pragma unroll
        for (int rr = 0; rr < 4; ++rr) {
            int c = wv * 16 + quad * 4 + rr;
            float v = acc[t][rr];
            size_t addr = obase + (size_t)c * PLANE + i;
            if (BF16OUT) ((ushortT*)outp)[addr] = f2bf(v);
            else         ((float*)outp)[addr] = v;
        }
    }
}

// ---------- Kernel 7: combine + residual + 2x2 maxpool ----------
__global__ __launch_bounds__(256) void final_kernel(
    const ushortT* __restrict__ houtT, const float* __restrict__ y_norm,
    const float* __restrict__ gamma,
    float* __restrict__ out, float* __restrict__ down)
{
    int blk = blockIdx.x;
    int tile = blk & 63;
    int bc = blk >> 6;
    int th = (tile >> 3) * 32;
    int tw = (tile & 7) * 32;
    __shared__ float t[32][33];
    const ushortT* hT = houtT + (size_t)bc * PLANE;
    {
        int ww = threadIdx.x >> 3;
        int hh = (threadIdx.x & 7) * 4;
        us4 v4 = *(const us4*)(hT + (size_t)(tw + ww) * Hh + th + hh);
        t[hh + 0][ww] = __uint_as_float((unsigned)v4[0] << 16);
        t[hh + 1][ww] = __uint_as_float((unsigned)v4[1] << 16);
        t[hh + 2][ww] = __uint_as_float((unsigned)v4[2] << 16);
        t[hh + 3][ww] = __uint_as_float((unsigned)v4[3] << 16);
    }
    __syncthreads();
    float g = gamma[0];
    int qw_ = threadIdx.x & 15;
    int qh_ = threadIdx.x >> 4;
    const float* yb = y_norm + (size_t)bc * PLANE;
    float* ob = out + (size_t)bc * PLANE;
    float mx = -1e30f;
    float2 res[2];
    #pragma unroll
    for (int i = 0; i < 2; ++i) {
        int hh = 2 * qh_ + i;
        int off = (th + hh) * Ww + tw + 2 * qw_;
        float2 v = *(const float2*)(ob + off);
        float2 y = *(const float2*)(yb + off);
        float o0 = g * (t[hh][2 * qw_]     + v.x) + y.x;
        float o1 = g * (t[hh][2 * qw_ + 1] + v.y) + y.y;
        res[i] = make_float2(o0, o1);
        mx = fmaxf(mx, fmaxf(o0, o1));
    }
    #pragma unroll
    for (int i = 0; i < 2; ++i) {
        int off = (th + 2 * qh_ + i) * Ww + tw + 2 * qw_;
        *(float2*)(ob + off) = res[i];
    }
    down[(size_t)bc * 16384 + (th / 2 + qh_) * 128 + tw / 2 + qw_] = mx;
}

extern "C" void kernel_launch(void* const* d_in, const int* in_sizes, int n_in,
                              void* d_out, int out_size, void* d_ws, size_t ws_size,
                              hipStream_t stream)
{
    const float* x     = (const float*)d_in[0];
    const float* hw    = (const float*)d_in[1];
    const float* hb    = (const float*)d_in[2];
    const float* vw    = (const float*)d_in[3];
    const float* vb    = (const float*)d_in[4];
    const float* pww   = (const float*)d_in[5];
    const float* pwb   = (const float*)d_in[6];
    const float* bnw   = (const float*)d_in[7];
    const float* bnb   = (const float*)d_in[8];
    const float* qw    = (const float*)d_in[9];
    const float* qb    = (const float*)d_in[10];
    const float* kw    = (const float*)d_in[11];
    const float* kb    = (const float*)d_in[12];
    const float* vw2   = (const float*)d_in[13];
    const float* vb2   = (const float*)d_in[14];
    const float* gamma = (const float*)d_in[15];

    float* ws = (float*)d_ws;
    const size_t NP = (size_t)Bn * Cc * PLANE;   // 16.7M
    const size_t NQ = (size_t)Bn * CQn * PLANE;  // 2.1M
    float* y_raw  = ws;                        // [NP]
    float* y_norm = ws + NP;                   // [NP]
    float* slotC  = ws + 2 * NP;               // a_buf bf16 -> valT bf16
    float* slotD  = ws + 2 * NP + NP / 2;      // valb bf16 -> houtT bf16
    float* ptr    = ws + 3 * NP;
    ushortT* qbuf = (ushortT*)ptr;             // NQ bf16
    ushortT* kbuf = qbuf + NQ;
    ushortT* qT   = kbuf + NQ;
    ushortT* kT   = qT + NQ;
    float* sums   = (float*)(kT + NQ);         // 256
    float* sumsq  = sums + 256;
    float* alpha  = sumsq + 256;
    float* beta   = alpha + 256;
    ushortT* pw_bf = (ushortT*)(beta + 256);
    ushortT* qk_bf = pw_bf + 64 * 64;
    ushortT* vw_bf = qk_bf + 16 * 64;

    ushortT* a_buf = (ushortT*)slotC;
    ushortT* valT  = (ushortT*)slotC;   // a_buf dead after pw
    ushortT* valb  = (ushortT*)slotD;
    ushortT* houtT = (ushortT*)slotD;   // valb dead after width attn
    float* out  = (float*)d_out;
    float* down = out + NP;

    hipMemsetAsync(sums, 0, 512 * sizeof(float), stream);
    pack_weights_kernel<<<dim3(16), dim3(256), 0, stream>>>(
        pww, qw, kw, vw2, pw_bf, qk_bf, vw_bf);
    dw_kernel<<<dim3(Bn * Cc * 16), dim3(256), 0, stream>>>(
        x, hw, hb, vw, vb, a_buf);
    pw_mfma_kernel<<<dim3(Bn * 256), dim3(256), 0, stream>>>(
        a_buf, pw_bf, pwb, y_raw, sums, sumsq);
    finalize_kernel<<<dim3(1), dim3(64), 0, stream>>>(
        sums, sumsq, bnw, bnb, alpha, beta);
    qkv_mfma_kernel<<<dim3(Bn * 256), dim3(256), 0, stream>>>(
        y_raw, alpha, beta, qk_bf, qb, kb, vw_bf, vb2,
        y_norm, qbuf, kbuf, valb);
    transpose16_kernel<<<dim3(Bn * CQn * 64), dim3(256), 0, stream>>>(qbuf, qT);
    transpose16_kernel<<<dim3(Bn * CQn * 64), dim3(256), 0, stream>>>(kbuf, kT);
    transpose16_kernel<<<dim3(Bn * Cc * 64), dim3(256), 0, stream>>>(valb, valT);
    attn_mfma2_kernel<false><<<dim3(Bn * Hh), dim3(256), 0, stream>>>(
        qbuf, kbuf, valb, (void*)out);
    attn_mfma2_kernel<true><<<dim3(Bn * Hh), dim3(256), 0, stream>>>(
        qT, kT, valT, (void*)houtT);
    final_kernel<<<dim3(Bn * Cc * 64), dim3(256), 0, stream>>>(
        houtT, y_norm, gamma, out, down);
}